// Round 7
// baseline (191.825 us; speedup 1.0000x reference)
//
#include <hip/hip_runtime.h>
#include <hip/hip_bf16.h>

// Shapes: B=4, LQ=LKV=1024, D=1024, H=16, HD=64, N=H*HD=1024, M=B*LQ=4096
// ws (u16, 56 MB): Aq 4M | Ac 4M | Wqt 1M | Wkt 1M | Wvt 1M | Wot 1M |
//                  qws 4M (x0.125) | kws 4M | vtws 4M (dim-major) | mws 4M

typedef unsigned short u16;
typedef __attribute__((ext_vector_type(8))) short short8;   // 8 bf16 = 4 VGPRs
typedef __attribute__((ext_vector_type(4))) float f32x4;

__device__ __forceinline__ float bf2f(u16 u) {
    union { unsigned int i; float f; } c;
    c.i = ((unsigned int)u) << 16;
    return c.f;
}

__device__ __forceinline__ u16 f2bf(float f) {
    unsigned int x = __float_as_uint(f);
    unsigned int r = (x + 0x7fffu + ((x >> 16) & 1u)) >> 16;  // RNE
    return (u16)r;
}

// async global->LDS, 16B/lane; lds base MUST be wave-uniform (HW adds lane*16)
__device__ __forceinline__ void glds16(u16* lds, const u16* g) {
    __builtin_amdgcn_global_load_lds(
        (const __attribute__((address_space(1))) void*)g,
        (__attribute__((address_space(3))) void*)lds, 16, 0, 0);
}

// raw-barrier discipline (no __syncthreads in pipelined loops: it drains vmcnt)
#define FENCE() asm volatile("" ::: "memory")
#define BAR() do { FENCE(); __builtin_amdgcn_s_barrier(); FENCE(); } while (0)
#define WAIT_VM8() do { asm volatile("s_waitcnt vmcnt(8)" ::: "memory"); \
                        __builtin_amdgcn_sched_barrier(0); } while (0)
#define WAIT_VM6() do { asm volatile("s_waitcnt vmcnt(6)" ::: "memory"); \
                        __builtin_amdgcn_sched_barrier(0); } while (0)
#define WAIT_VM4() do { asm volatile("s_waitcnt vmcnt(4)" ::: "memory"); \
                        __builtin_amdgcn_sched_barrier(0); } while (0)
#define WAIT_VM0() do { asm volatile("s_waitcnt vmcnt(0)" ::: "memory"); \
                        __builtin_amdgcn_sched_barrier(0); } while (0)

// ---------------------------------------------------------------------------
// Fused pre-pass, flat grid 5120 blocks x 256 thr (unchanged)
// ---------------------------------------------------------------------------
__global__ __launch_bounds__(256) void prep(
    const float* __restrict__ q, const float* __restrict__ ctx,
    const float* __restrict__ Wq, const float* __restrict__ Wk,
    const float* __restrict__ Wv, const float* __restrict__ Wo,
    u16* __restrict__ Aq, u16* __restrict__ Ac,
    u16* __restrict__ Wqt, u16* __restrict__ Wkt,
    u16* __restrict__ Wvt, u16* __restrict__ Wot)
{
    __shared__ float ls[64][65];
    const int t = threadIdx.x;
    int bid = blockIdx.x;

    if (bid < 4096) {
        const float* in = (bid < 2048) ? q : ctx;
        u16* out = (bid < 2048) ? Aq : Ac;
        size_t i = ((size_t)(bid & 2047) * 256 + t) * 8;
        float4 v0 = *(const float4*)(in + i);
        float4 v1 = *(const float4*)(in + i + 4);
        short8 p;
        p[0] = (short)f2bf(v0.x); p[1] = (short)f2bf(v0.y);
        p[2] = (short)f2bf(v0.z); p[3] = (short)f2bf(v0.w);
        p[4] = (short)f2bf(v1.x); p[5] = (short)f2bf(v1.y);
        p[6] = (short)f2bf(v1.z); p[7] = (short)f2bf(v1.w);
        *(short8*)(out + i) = p;
        return;
    }
    bid -= 4096;
    const float* in; u16* out; int C; size_t moff; int rt, ct;
    if (bid < 768) {
        const int m = bid >> 8, idx = bid & 255;
        in = (m == 0) ? Wq : (m == 1) ? Wk : Wv;
        out = (m == 0) ? Wqt : (m == 1) ? Wkt : Wvt;
        C = 64; rt = (idx & 15) * 64; ct = 0; moff = (size_t)(idx >> 4) * 65536;
    } else {
        const int idx = bid - 768;
        in = Wo; out = Wot; C = 1024; moff = 0;
        rt = (idx & 15) * 64; ct = (idx >> 4) * 64;
    }
    #pragma unroll
    for (int i = 0; i < 4; ++i) {
        int s = i * 256 + t;
        int row = s >> 4, chunk = s & 15;
        float4 v = *(const float4*)(in + moff + (size_t)(rt + row) * C + ct + chunk * 4);
        ls[row][chunk * 4 + 0] = v.x;
        ls[row][chunk * 4 + 1] = v.y;
        ls[row][chunk * 4 + 2] = v.z;
        ls[row][chunk * 4 + 3] = v.w;
    }
    __syncthreads();
    #pragma unroll
    for (int i = 0; i < 2; ++i) {
        int s = i * 256 + t;
        int n = s >> 3, kc = s & 7;
        short8 p;
        #pragma unroll
        for (int j = 0; j < 8; ++j) p[j] = (short)f2bf(ls[kc * 8 + j][n]);
        *(short8*)(out + moff + (size_t)(ct + n) * 1024 + rt + kc * 8) = p;
    }
}

// ---------------------------------------------------------------------------
// Q/K/V projection v7 (gemm_qkv4): 128x128 tile, BK=64, 2-phase counted dbuf,
// 8 waves x 512 thr (per-wave 64x32 out). TLP fix: v6's counters showed the
// MFMA pipe busy exactly its 10us floor and 61% dual-idle cycles — a latency
// stall at 2 waves/SIMD. 8-wave blocks + launch_bounds(512,4) keep 64 KB LDS
// and ~110 VGPR -> 2 blocks/CU = 4 waves/SIMD (2x TLP). Schedule/swizzle/
// epilogue semantics carried over bit-identical; stage = 4 glds16/thread so
// steady-state wait is vmcnt(4).
// ---------------------------------------------------------------------------
__global__ __launch_bounds__(512, 4) void gemm_qkv4(
    const u16* __restrict__ Aq, const u16* __restrict__ Ac,
    const u16* __restrict__ Wqt, const u16* __restrict__ Wkt,
    const u16* __restrict__ Wvt,
    const float* __restrict__ bq, const float* __restrict__ bk,
    const float* __restrict__ bv,
    u16* __restrict__ qws, u16* __restrict__ kws, u16* __restrict__ vtws)
{
    __shared__ u16 As[2][128 * 64];   // 32 KB
    __shared__ u16 Bs[2][128 * 64];   // 32 KB
    const int tid = threadIdx.x;
    const int w = tid >> 6, lane = tid & 63;
    const int wr = w >> 2, wc = w & 3;                 // 2 row-halves x 4 col-quarters
    const int quad = lane >> 4, c = lane & 15, cx = c & 7;

    // 768 blocks: xcd = f&7 owns 4 mtiles x 8 nt x 3 z (96 blocks)
    const int f = blockIdx.x;
    const int xcd = f & 7, r = f >> 3;                 // r 0..95
    const int z = r >> 5;                              // 0..2
    const int rr_ = r & 31;
    const int mt = xcd * 4 + (rr_ & 3);                // 0..31
    const int nt = rr_ >> 2;                           // 0..7
    const int m0 = mt * 128, n0 = nt * 128;

    const u16* A = (z == 0) ? Aq : Ac;
    const u16* Wt = (z == 0) ? Wqt : (z == 1) ? Wkt : Wvt;
    const float* bias = (z == 0) ? bq : (z == 1) ? bk : bv;

    const int sr = tid >> 3;                           // 0..63
    const int gch = (tid & 7) ^ (sr & 7);              // source-side swizzle
    const u16* gA = A + (size_t)(m0 + sr) * 1024 + gch * 8;
    const u16* gB = Wt + (size_t)(n0 + sr) * 1024 + gch * 8;

    // full 128x64 A + B tile: 4 glds16 per thread (rows sr and 64+sr)
    auto stage = [&](int par, int tk) {
        glds16(As[par] + (w * 8) * 64,        gA + (size_t)tk * 64);
        glds16(As[par] + ((64 + w * 8)) * 64, gA + (size_t)64 * 1024 + tk * 64);
        glds16(Bs[par] + (w * 8) * 64,        gB + (size_t)tk * 64);
        glds16(Bs[par] + ((64 + w * 8)) * 64, gB + (size_t)64 * 1024 + tk * 64);
    };

    f32x4 acc[4][2] = {};          // [mf][nf]

    stage(0, 0);
    stage(1, 1);
    // outstanding: 8. steady state: wait(4) -> tile i landed, tile i+1 in flight.
    #pragma unroll 1
    for (int i = 0; i < 16; ++i) {
        const int cur = i & 1;
        if (i < 15) { WAIT_VM4(); } else { WAIT_VM0(); }
        BAR();
        short8 af[4][2], bf[2][2];
        #pragma unroll
        for (int mf = 0; mf < 4; ++mf)
            #pragma unroll
            for (int ks = 0; ks < 2; ++ks)
                af[mf][ks] = *(const short8*)&As[cur][
                    (wr * 64 + mf * 16 + c) * 64 + (((ks * 4 + quad) ^ cx) * 8)];
        #pragma unroll
        for (int nf = 0; nf < 2; ++nf)
            #pragma unroll
            for (int ks = 0; ks < 2; ++ks)
                bf[nf][ks] = *(const short8*)&Bs[cur][
                    (wc * 32 + nf * 16 + c) * 64 + (((ks * 4 + quad) ^ cx) * 8)];
        #pragma unroll
        for (int mf = 0; mf < 4; ++mf)
            #pragma unroll
            for (int nf = 0; nf < 2; ++nf)
                #pragma unroll
                for (int ks = 0; ks < 2; ++ks)
                    acc[mf][nf] = __builtin_amdgcn_mfma_f32_16x16x32_bf16(
                        af[mf][ks], bf[nf][ks], acc[mf][nf], 0, 0, 0);
        BAR();                       // all waves done reading buf cur
        if (i < 14) stage(cur, i + 2);
    }

    // ---- epilogue ----
    // cols: n0 + wc*32 + nf*16 + c -> head h = nt*2 + (wc>>1), hd = (wc&1)*32+...
    const int h = nt * 2 + (wc >> 1);
    const int hd0 = (wc & 1) * 32;
    const int b = m0 >> 10;                    // 128-row tile never crosses batch
    const int lbase = (m0 & 1023) + wr * 64;

    float bb[2];
    #pragma unroll
    for (int nf = 0; nf < 2; ++nf) bb[nf] = bias[h * 64 + hd0 + nf * 16 + c];

    if (z < 2) {
        u16* dst = (z == 0) ? qws : kws;
        const float scale = (z == 0) ? 0.125f : 1.0f;
        u16* dbase = dst + (size_t)(b * 16 + h) * 1024 * 64;
        #pragma unroll
        for (int mf = 0; mf < 4; ++mf) {
            const int rowb = lbase + mf * 16 + quad * 4;
            #pragma unroll
            for (int rw = 0; rw < 4; ++rw) {
                u16* drow = dbase + (size_t)(rowb + rw) * 64;
                #pragma unroll
                for (int nf = 0; nf < 2; ++nf)
                    drow[hd0 + nf * 16 + c] = f2bf((acc[mf][nf][rw] + bb[nf]) * scale);
            }
        }
    } else {
        // V: vtws [B,H,64,1024] dim-major; 4 acc regs = 4 consecutive l -> ushort4
        u16* dbase = vtws + (size_t)(b * 16 + h) * 64 * 1024;
        #pragma unroll
        for (int mf = 0; mf < 4; ++mf) {
            const int l0 = lbase + mf * 16 + quad * 4;
            #pragma unroll
            for (int nf = 0; nf < 2; ++nf) {
                const int hd = hd0 + nf * 16 + c;
                ushort4 pk;
                pk.x = f2bf(acc[mf][nf][0] + bb[nf]);
                pk.y = f2bf(acc[mf][nf][1] + bb[nf]);
                pk.z = f2bf(acc[mf][nf][2] + bb[nf]);
                pk.w = f2bf(acc[mf][nf][3] + bb[nf]);
                *(ushort4*)(dbase + (size_t)hd * 1024 + l0) = pk;
            }
        }
    }
}

// ---------------------------------------------------------------------------
// Output projection v4: 2-phase counted pipeline (unchanged this round)
// ---------------------------------------------------------------------------
__global__ __launch_bounds__(256) void gemm_out(
    const u16* __restrict__ A, const u16* __restrict__ Wot,
    const float* __restrict__ bo, float* __restrict__ out)
{
    __shared__ u16 As[2][128 * 64];   // 32 KB
    __shared__ u16 Bs[2][64 * 64];    // 16 KB
    const int f = blockIdx.x;
    const int xcd = f & 7, k = f >> 3;
    const int m0 = (xcd * 4 + (k & 3)) * 128;
    const int n0 = (k >> 2) * 64;
    const int t = threadIdx.x;
    const int w = t >> 6, lane = t & 63;
    const int quad = lane >> 4, c = lane & 15;
    const int cx = c & 7;

    const int sr = w * 8 + (lane >> 3);
    const int gch = (lane & 7) ^ ((lane >> 3) & 7);
    const u16* gA = A + (size_t)(m0 + sr) * 1024 + gch * 8;
    const u16* gB = Wot + (size_t)(n0 + sr) * 1024 + gch * 8;

    const int arow = (w >> 1) * 64 + c;
    const int brow = (w & 1) * 32 + c;

    auto stage = [&](int par, int kt) {        // 6 glds16 per thread
        #pragma unroll
        for (int i = 0; i < 4; ++i)
            glds16(As[par] + (i * 32 + w * 8) * 64, gA + (size_t)i * 32 * 1024 + kt);
        #pragma unroll
        for (int i = 0; i < 2; ++i)
            glds16(Bs[par] + (i * 32 + w * 8) * 64, gB + (size_t)i * 32 * 1024 + kt);
    };

    f32x4 acc[4][2] = {};
    stage(0, 0);
    stage(1, 64);
    // outstanding: 12. steady state: wait(6) -> tile i landed, tile i+1 in flight.
    #pragma unroll 1
    for (int i = 0; i < 16; ++i) {
        const int cur = i & 1;
        if (i < 15) { WAIT_VM6(); } else { WAIT_VM0(); }
        BAR();
        #pragma unroll
        for (int kh = 0; kh < 2; ++kh) {
            const int ch = (kh * 4 + quad);
            short8 af[4], bf[2];
            #pragma unroll
            for (int rs = 0; rs < 4; ++rs)
                af[rs] = *(const short8*)(As[cur] + (arow + rs * 16) * 64 + (ch ^ cx) * 8);
            #pragma unroll
            for (int cs = 0; cs < 2; ++cs)
                bf[cs] = *(const short8*)(Bs[cur] + (brow + cs * 16) * 64 + (ch ^ cx) * 8);
            #pragma unroll
            for (int rs = 0; rs < 4; ++rs)
                #pragma unroll
                for (int cs = 0; cs < 2; ++cs)
                    acc[rs][cs] = __builtin_amdgcn_mfma_f32_16x16x32_bf16(
                        af[rs], bf[cs], acc[rs][cs], 0, 0, 0);
        }
        BAR();                       // all waves done reading buf cur
        if (i < 14) stage(cur, (i + 2) * 64);
    }

    const int nb = n0 + (w & 1) * 32;
    float bb[2];
    #pragma unroll
    for (int cs = 0; cs < 2; ++cs) bb[cs] = bo[nb + cs * 16 + c];

    #pragma unroll
    for (int rs = 0; rs < 4; ++rs) {
        #pragma unroll
        for (int r = 0; r < 4; ++r) {
            const int row = m0 + (w >> 1) * 64 + rs * 16 + quad * 4 + r;
            float* orow = out + (size_t)row * 1024 + nb;
            #pragma unroll
            for (int cs = 0; cs < 2; ++cs)
                orow[cs * 16 + c] = acc[rs][cs][r] + bb[cs];
        }
    }
}

// ---------------------------------------------------------------------------
// MFMA flash attention v8: 32 q-rows per wave, dbuf + counted vmcnt(4)
// (unchanged this round)
// ---------------------------------------------------------------------------
__global__ __launch_bounds__(256) void attn_mfma(
    const u16* __restrict__ qws, const u16* __restrict__ kws,
    const u16* __restrict__ vtws, u16* __restrict__ multi,
    float* __restrict__ resid)
{
    __shared__ u16 Ks[2][64 * 64];     // [par][key][dim], chunk-swizzled (16 KB)
    __shared__ u16 Vs[2][64 * 64];     // [par][dim][key], chunk-swizzled (16 KB)
    __shared__ u16 Ps[4][16 * 64];     // per-wave P [16][64], chunk-XOR swizzled (8 KB)
    const int t = threadIdx.x;
    const int wave = t >> 6, lane = t & 63;
    const int quad = lane >> 4, c = lane & 15;
    const int cx = c & 7;
    const int f = blockIdx.x;                  // 512 blocks
    const int xcd = f & 7, j = f >> 3;         // j 0..63
    const int bh = xcd * 8 + (j & 7);          // 8 heads per XCD (KV L2-resident)
    const int qt = j >> 3;                     // 0..7
    const int b = bh >> 4, h = bh & 15;
    const int q0 = qt * 128 + wave * 32;       // 32 q-rows per wave

    const u16* qb = qws + ((size_t)bh * 1024 + q0) * 64;
    const u16* kb = kws + (size_t)bh * 65536;
    const u16* vb = vtws + (size_t)bh * 65536;

    // Q fragments for 2 row-blocks (rows rb*16 + c), k-halves 0/1
    short8 qa[2][2];
    #pragma unroll
    for (int rb = 0; rb < 2; ++rb) {
        qa[rb][0] = *(const short8*)(qb + (size_t)(rb * 16 + c) * 64 + quad * 8);
        qa[rb][1] = *(const short8*)(qb + (size_t)(rb * 16 + c) * 64 + 32 + quad * 8);
    }

    const int srow = wave * 16 + (lane >> 3);
    const int gch = (lane & 7) ^ ((lane >> 3) & 7);
    const u16* gK0 = kb + (size_t)srow * 64 + gch * 8;
    const u16* gK1 = kb + (size_t)(srow + 8) * 64 + gch * 8;
    const u16* gV0 = vb + (size_t)srow * 1024 + gch * 8;
    const u16* gV1 = vb + (size_t)(srow + 8) * 1024 + gch * 8;

    // 4 glds16 per stage -> vmcnt +4; steady-state outstanding = 8 (2 tiles)
    auto stage = [&](int par, int kt) {
        glds16(Ks[par] + (wave * 16) * 64,     gK0 + (size_t)kt * 64);
        glds16(Ks[par] + (wave * 16 + 8) * 64, gK1 + (size_t)kt * 64);
        glds16(Vs[par] + (wave * 16) * 64,     gV0 + kt);
        glds16(Vs[par] + (wave * 16 + 8) * 64, gV1 + kt);
    };

    f32x4 O[2][4] = {};                // [rb][nt]
    float ps[2][4] = {};               // [rb][r]
    u16* pw = &Ps[wave][0];

    stage(0, 0);
    stage(1, 64);

    #pragma unroll 1
    for (int i = 0; i < 16; ++i) {
        const int cur = i & 1;
        if (i < 15) { WAIT_VM4(); } else { WAIT_VM0(); }  // tile i landed
        BAR();

        const u16* Kc = Ks[cur];
        const u16* Vc = Vs[cur];

        // hoist K/V fragments once per tile; reused by both row-blocks
        short8 kf[4][2], vf[4][2];
        #pragma unroll
        for (int nt = 0; nt < 4; ++nt) {
            const u16* kr = Kc + (nt * 16 + c) * 64;
            kf[nt][0] = *(const short8*)(kr + ((quad ^ cx)) * 8);
            kf[nt][1] = *(const short8*)(kr + (((4 + quad) ^ cx)) * 8);
            const u16* vr = Vc + (nt * 16 + c) * 64;
            vf[nt][0] = *(const short8*)(vr + ((quad ^ cx)) * 8);
            vf[nt][1] = *(const short8*)(vr + (((4 + quad) ^ cx)) * 8);
        }

        #pragma unroll
        for (int rb = 0; rb < 2; ++rb) {
            f32x4 s[4];
            __builtin_amdgcn_s_setprio(1);
            #pragma unroll
            for (int nt = 0; nt < 4; ++nt) {
                f32x4 z = {};
                z = __builtin_amdgcn_mfma_f32_16x16x32_bf16(qa[rb][0], kf[nt][0], z, 0, 0, 0);
                z = __builtin_amdgcn_mfma_f32_16x16x32_bf16(qa[rb][1], kf[nt][1], z, 0, 0, 0);
                s[nt] = z;
            }
            __builtin_amdgcn_s_setprio(0);

            // P store: row prow = quad*4+r, col = nt*16+c; chunk' = chunk ^ (prow&7)
            #pragma unroll
            for (int nt = 0; nt < 4; ++nt)
                #pragma unroll
                for (int r = 0; r < 4; ++r) {
                    float p = __expf(s[nt][r]);
                    ps[rb][r] += p;
                    const int prow = quad * 4 + r;
                    pw[prow * 64 + (((nt * 2 + (c >> 3)) ^ (prow & 7)) * 8) + (c & 7)]
                        = (u16)(__float_as_uint(p) >> 16);
                }
            short8 pa0 = *(const short8*)(pw + c * 64 + ((quad ^ cx)) * 8);
            short8 pa1 = *(const short8*)(pw + c * 64 + (((4 + quad) ^ cx)) * 8);

            __builtin_amdgcn_s_setprio(1);
            #pragma unroll
            for (int nt = 0; nt < 4; ++nt) {
                O[rb][nt] = __builtin_amdgcn_mfma_f32_16x16x32_bf16(pa0, vf[nt][0], O[rb][nt], 0, 0, 0);
                O[rb][nt] = __builtin_amdgcn_mfma_f32_16x16x32_bf16(pa1, vf[nt][1], O[rb][nt], 0, 0, 0);
            }
            __builtin_amdgcn_s_setprio(0);
        }

        BAR();                         // all waves done reading buf cur
        if (i < 14) stage(cur, (i + 2) * 64);
    }

    #pragma unroll
    for (int rb = 0; rb < 2; ++rb) {
        float inv[4];
        #pragma unroll
        for (int r = 0; r < 4; ++r) {
            float sum = ps[rb][r];
            sum += __shfl_xor(sum, 1);
            sum += __shfl_xor(sum, 2);
            sum += __shfl_xor(sum, 4);
            sum += __shfl_xor(sum, 8);
            inv[r] = 1.0f / sum;
        }
        u16* ob = multi + ((size_t)b * 1024 + q0 + rb * 16 + quad * 4) * 1024 + h * 64 + c;
        #pragma unroll
        for (int r = 0; r < 4; ++r) {
            u16* orow = ob + (size_t)r * 1024;
            orow[0]  = f2bf(O[rb][0][r] * inv[r]);
            orow[16] = f2bf(O[rb][1][r] * inv[r]);
            orow[32] = f2bf(O[rb][2][r] * inv[r]);
            orow[48] = f2bf(O[rb][3][r] * inv[r]);
        }

        // resid epilogue: lane holds Q[q0+rb*16+c][quad*8..] in qa[rb] (scaled 1/8)
        float* rr = resid + ((size_t)b * 1024 + q0 + rb * 16 + c) * 1024 + h * 64;
        #pragma unroll
        for (int jj = 0; jj < 8; ++jj) {
            rr[quad * 8 + jj]      = bf2f((u16)qa[rb][0][jj]) * 8.0f;
            rr[32 + quad * 8 + jj] = bf2f((u16)qa[rb][1][jj]) * 8.0f;
        }
    }
}

extern "C" void kernel_launch(void* const* d_in, const int* in_sizes, int n_in,
                              void* d_out, int out_size, void* d_ws, size_t ws_size,
                              hipStream_t stream) {
    const float* queries = (const float*)d_in[0];
    const float* context = (const float*)d_in[1];
    const float* Wq = (const float*)d_in[2];
    const float* bq = (const float*)d_in[3];
    const float* Wk = (const float*)d_in[4];
    const float* bk = (const float*)d_in[5];
    const float* Wv = (const float*)d_in[6];
    const float* bv = (const float*)d_in[7];
    const float* Wo = (const float*)d_in[8];
    const float* bo = (const float*)d_in[9];

    float* out = (float*)d_out;                     // [4,1024,1024] f32
    float* resid = out + (size_t)4 * 1024 * 1024;   // [4,1024,1024] f32

    const size_t M1 = 1024 * 1024;
    u16* Aq   = (u16*)d_ws;          // 4M
    u16* Ac   = Aq + 4 * M1;         // 4M
    u16* Wqt  = Ac + 4 * M1;         // 1M
    u16* Wkt  = Wqt + M1;            // 1M
    u16* Wvt  = Wkt + M1;            // 1M
    u16* Wot  = Wvt + M1;            // 1M
    u16* qws  = Wot + M1;            // 4M (pre-scaled 0.125)
    u16* kws  = qws + 4 * M1;        // 4M
    u16* vtws = kws + 4 * M1;        // 4M [B,H,64,1024]
    u16* mws  = vtws + 4 * M1;       // 4M [B,1024,1024]

    prep<<<5120, 256, 0, stream>>>(queries, context, Wq, Wk, Wv, Wo,
                                   Aq, Ac, Wqt, Wkt, Wvt, Wot);
    gemm_qkv4<<<768, 512, 0, stream>>>(Aq, Ac, Wqt, Wkt, Wvt,
                                       bq, bk, bv, qws, kws, vtws);
    attn_mfma<<<512, 256, 0, stream>>>(qws, kws, vtws, mws, resid);
    gemm_out<<<512, 256, 0, stream>>>(mws, Wot, bo, out);
}

// Round 8
// 190.738 us; speedup vs baseline: 1.0057x; 1.0057x over previous
//
#include <hip/hip_runtime.h>
#include <hip/hip_bf16.h>

// Shapes: B=4, LQ=LKV=1024, D=1024, H=16, HD=64, N=H*HD=1024, M=B*LQ=4096
// ws (u16, 56 MB): Aq 4M | Ac 4M | Wqt 1M | Wkt 1M | Wvt 1M | Wot 1M |
//                  qws 4M (x0.125) | kws 4M | vtws 4M (dim-major) | mws 4M

typedef unsigned short u16;
typedef __attribute__((ext_vector_type(8))) short short8;   // 8 bf16 = 4 VGPRs
typedef __attribute__((ext_vector_type(4))) float f32x4;

__device__ __forceinline__ float bf2f(u16 u) {
    union { unsigned int i; float f; } c;
    c.i = ((unsigned int)u) << 16;
    return c.f;
}

__device__ __forceinline__ u16 f2bf(float f) {
    unsigned int x = __float_as_uint(f);
    unsigned int r = (x + 0x7fffu + ((x >> 16) & 1u)) >> 16;  // RNE
    return (u16)r;
}

// async global->LDS, 16B/lane; lds base MUST be wave-uniform (HW adds lane*16)
__device__ __forceinline__ void glds16(u16* lds, const u16* g) {
    __builtin_amdgcn_global_load_lds(
        (const __attribute__((address_space(1))) void*)g,
        (__attribute__((address_space(3))) void*)lds, 16, 0, 0);
}

// raw-barrier discipline (no __syncthreads in pipelined loops: it drains vmcnt)
#define FENCE() asm volatile("" ::: "memory")
#define BAR() do { FENCE(); __builtin_amdgcn_s_barrier(); FENCE(); } while (0)
#define WAIT_VM8() do { asm volatile("s_waitcnt vmcnt(8)" ::: "memory"); \
                        __builtin_amdgcn_sched_barrier(0); } while (0)
#define WAIT_VM6() do { asm volatile("s_waitcnt vmcnt(6)" ::: "memory"); \
                        __builtin_amdgcn_sched_barrier(0); } while (0)
#define WAIT_VM4() do { asm volatile("s_waitcnt vmcnt(4)" ::: "memory"); \
                        __builtin_amdgcn_sched_barrier(0); } while (0)
#define WAIT_VM2() do { asm volatile("s_waitcnt vmcnt(2)" ::: "memory"); \
                        __builtin_amdgcn_sched_barrier(0); } while (0)
#define WAIT_VM0() do { asm volatile("s_waitcnt vmcnt(0)" ::: "memory"); \
                        __builtin_amdgcn_sched_barrier(0); } while (0)

// ---------------------------------------------------------------------------
// Fused pre-pass, flat grid 5120 blocks x 256 thr (unchanged)
// ---------------------------------------------------------------------------
__global__ __launch_bounds__(256) void prep(
    const float* __restrict__ q, const float* __restrict__ ctx,
    const float* __restrict__ Wq, const float* __restrict__ Wk,
    const float* __restrict__ Wv, const float* __restrict__ Wo,
    u16* __restrict__ Aq, u16* __restrict__ Ac,
    u16* __restrict__ Wqt, u16* __restrict__ Wkt,
    u16* __restrict__ Wvt, u16* __restrict__ Wot)
{
    __shared__ float ls[64][65];
    const int t = threadIdx.x;
    int bid = blockIdx.x;

    if (bid < 4096) {
        const float* in = (bid < 2048) ? q : ctx;
        u16* out = (bid < 2048) ? Aq : Ac;
        size_t i = ((size_t)(bid & 2047) * 256 + t) * 8;
        float4 v0 = *(const float4*)(in + i);
        float4 v1 = *(const float4*)(in + i + 4);
        short8 p;
        p[0] = (short)f2bf(v0.x); p[1] = (short)f2bf(v0.y);
        p[2] = (short)f2bf(v0.z); p[3] = (short)f2bf(v0.w);
        p[4] = (short)f2bf(v1.x); p[5] = (short)f2bf(v1.y);
        p[6] = (short)f2bf(v1.z); p[7] = (short)f2bf(v1.w);
        *(short8*)(out + i) = p;
        return;
    }
    bid -= 4096;
    const float* in; u16* out; int C; size_t moff; int rt, ct;
    if (bid < 768) {
        const int m = bid >> 8, idx = bid & 255;
        in = (m == 0) ? Wq : (m == 1) ? Wk : Wv;
        out = (m == 0) ? Wqt : (m == 1) ? Wkt : Wvt;
        C = 64; rt = (idx & 15) * 64; ct = 0; moff = (size_t)(idx >> 4) * 65536;
    } else {
        const int idx = bid - 768;
        in = Wo; out = Wot; C = 1024; moff = 0;
        rt = (idx & 15) * 64; ct = (idx >> 4) * 64;
    }
    #pragma unroll
    for (int i = 0; i < 4; ++i) {
        int s = i * 256 + t;
        int row = s >> 4, chunk = s & 15;
        float4 v = *(const float4*)(in + moff + (size_t)(rt + row) * C + ct + chunk * 4);
        ls[row][chunk * 4 + 0] = v.x;
        ls[row][chunk * 4 + 1] = v.y;
        ls[row][chunk * 4 + 2] = v.z;
        ls[row][chunk * 4 + 3] = v.w;
    }
    __syncthreads();
    #pragma unroll
    for (int i = 0; i < 2; ++i) {
        int s = i * 256 + t;
        int n = s >> 3, kc = s & 7;
        short8 p;
        #pragma unroll
        for (int j = 0; j < 8; ++j) p[j] = (short)f2bf(ls[kc * 8 + j][n]);
        *(short8*)(out + moff + (size_t)(ct + n) * 1024 + rt + kc * 8) = p;
    }
}

// ---------------------------------------------------------------------------
// Q/K/V projection v6 (gemm_qkv3): 128x128 tile, BK=64, 2-phase counted dbuf.
// Best directly-measured variant (41.6 us). Reverted here after the 8-wave
// TLP experiment (qkv4) regressed — five structures all land ~42 us, so the
// schedule axis is exhausted for this shape.
// ---------------------------------------------------------------------------
__global__ __launch_bounds__(256, 2) void gemm_qkv3(
    const u16* __restrict__ Aq, const u16* __restrict__ Ac,
    const u16* __restrict__ Wqt, const u16* __restrict__ Wkt,
    const u16* __restrict__ Wvt,
    const float* __restrict__ bq, const float* __restrict__ bk,
    const float* __restrict__ bv,
    u16* __restrict__ qws, u16* __restrict__ kws, u16* __restrict__ vtws)
{
    __shared__ u16 As[2][128 * 64];   // 32 KB
    __shared__ u16 Bs[2][128 * 64];   // 32 KB
    const int t = threadIdx.x;
    const int w = t >> 6, lane = t & 63;
    const int wr = w >> 1, wc = w & 1;                 // 2 x 2 wave grid
    const int quad = lane >> 4, c = lane & 15, cx = c & 7;

    // 768 blocks: xcd = f&7 owns 4 mtiles x 8 nt x 3 z (96 blocks)
    const int f = blockIdx.x;
    const int xcd = f & 7, r = f >> 3;                 // r 0..95
    const int z = r >> 5;                              // 0..2
    const int rr_ = r & 31;
    const int mt = xcd * 4 + (rr_ & 3);                // 0..31
    const int nt = rr_ >> 2;                           // 0..7
    const int m0 = mt * 128, n0 = nt * 128;

    const u16* A = (z == 0) ? Aq : Ac;
    const u16* Wt = (z == 0) ? Wqt : (z == 1) ? Wkt : Wvt;
    const float* bias = (z == 0) ? bq : (z == 1) ? bk : bv;

    const int sr = w * 8 + (lane >> 3);                // 0..31
    const int gch = (lane & 7) ^ ((lane >> 3) & 7);    // source-side swizzle
    const u16* gA = A + (size_t)(m0 + sr) * 1024 + gch * 8;
    const u16* gB = Wt + (size_t)(n0 + sr) * 1024 + gch * 8;

    // one 128x64 A tile + 128x64 B tile: 8 glds16 per thread
    auto stage = [&](int par, int tk) {
        #pragma unroll
        for (int i = 0; i < 4; ++i) {
            glds16(As[par] + (i * 32 + w * 8) * 64, gA + (size_t)(i * 32) * 1024 + tk * 64);
            glds16(Bs[par] + (i * 32 + w * 8) * 64, gB + (size_t)(i * 32) * 1024 + tk * 64);
        }
    };

    f32x4 acc[4][4] = {};          // [mf][nf]

    stage(0, 0);
    stage(1, 1);
    // outstanding: 16. steady state: wait(8) -> tile i landed, tile i+1 in flight.
    #pragma unroll 1
    for (int i = 0; i < 16; ++i) {
        const int cur = i & 1;
        if (i < 15) { WAIT_VM8(); } else { WAIT_VM0(); }
        BAR();
        short8 af[4][2], bf[4][2];
        #pragma unroll
        for (int mf = 0; mf < 4; ++mf)
            #pragma unroll
            for (int ks = 0; ks < 2; ++ks)
                af[mf][ks] = *(const short8*)&As[cur][
                    (wr * 64 + mf * 16 + c) * 64 + (((ks * 4 + quad) ^ cx) * 8)];
        #pragma unroll
        for (int nf = 0; nf < 4; ++nf)
            #pragma unroll
            for (int ks = 0; ks < 2; ++ks)
                bf[nf][ks] = *(const short8*)&Bs[cur][
                    (wc * 64 + nf * 16 + c) * 64 + (((ks * 4 + quad) ^ cx) * 8)];
        #pragma unroll
        for (int mf = 0; mf < 4; ++mf)
            #pragma unroll
            for (int nf = 0; nf < 4; ++nf)
                #pragma unroll
                for (int ks = 0; ks < 2; ++ks)
                    acc[mf][nf] = __builtin_amdgcn_mfma_f32_16x16x32_bf16(
                        af[mf][ks], bf[nf][ks], acc[mf][nf], 0, 0, 0);
        BAR();                       // all waves done reading buf cur
        if (i < 14) stage(cur, i + 2);
    }

    // ---- epilogue ----
    const int h = nt * 2 + wc;                 // wave wc owns one head
    const int b = m0 >> 10;                    // 128-row tile never crosses batch
    const int lbase = (m0 & 1023) + wr * 64;

    float bb[4];
    #pragma unroll
    for (int nf = 0; nf < 4; ++nf) bb[nf] = bias[h * 64 + nf * 16 + c];

    if (z < 2) {
        u16* dst = (z == 0) ? qws : kws;
        const float scale = (z == 0) ? 0.125f : 1.0f;
        u16* dbase = dst + (size_t)(b * 16 + h) * 1024 * 64;
        #pragma unroll
        for (int mf = 0; mf < 4; ++mf) {
            const int rowb = lbase + mf * 16 + quad * 4;
            #pragma unroll
            for (int rw = 0; rw < 4; ++rw) {
                u16* drow = dbase + (size_t)(rowb + rw) * 64;
                #pragma unroll
                for (int nf = 0; nf < 4; ++nf)
                    drow[nf * 16 + c] = f2bf((acc[mf][nf][rw] + bb[nf]) * scale);
            }
        }
    } else {
        // V: vtws [B,H,64,1024] dim-major; 4 acc regs = 4 consecutive l -> ushort4
        u16* dbase = vtws + (size_t)(b * 16 + h) * 64 * 1024;
        #pragma unroll
        for (int mf = 0; mf < 4; ++mf) {
            const int l0 = lbase + mf * 16 + quad * 4;
            #pragma unroll
            for (int nf = 0; nf < 4; ++nf) {
                const int hd = nf * 16 + c;
                ushort4 pk;
                pk.x = f2bf(acc[mf][nf][0] + bb[nf]);
                pk.y = f2bf(acc[mf][nf][1] + bb[nf]);
                pk.z = f2bf(acc[mf][nf][2] + bb[nf]);
                pk.w = f2bf(acc[mf][nf][3] + bb[nf]);
                *(ushort4*)(dbase + (size_t)hd * 1024 + l0) = pk;
            }
        }
    }
}

// ---------------------------------------------------------------------------
// Output projection v4: 2-phase counted pipeline (unchanged this round)
// ---------------------------------------------------------------------------
__global__ __launch_bounds__(256) void gemm_out(
    const u16* __restrict__ A, const u16* __restrict__ Wot,
    const float* __restrict__ bo, float* __restrict__ out)
{
    __shared__ u16 As[2][128 * 64];   // 32 KB
    __shared__ u16 Bs[2][64 * 64];    // 16 KB
    const int f = blockIdx.x;
    const int xcd = f & 7, k = f >> 3;
    const int m0 = (xcd * 4 + (k & 3)) * 128;
    const int n0 = (k >> 2) * 64;
    const int t = threadIdx.x;
    const int w = t >> 6, lane = t & 63;
    const int quad = lane >> 4, c = lane & 15;
    const int cx = c & 7;

    const int sr = w * 8 + (lane >> 3);
    const int gch = (lane & 7) ^ ((lane >> 3) & 7);
    const u16* gA = A + (size_t)(m0 + sr) * 1024 + gch * 8;
    const u16* gB = Wot + (size_t)(n0 + sr) * 1024 + gch * 8;

    const int arow = (w >> 1) * 64 + c;
    const int brow = (w & 1) * 32 + c;

    auto stage = [&](int par, int kt) {        // 6 glds16 per thread
        #pragma unroll
        for (int i = 0; i < 4; ++i)
            glds16(As[par] + (i * 32 + w * 8) * 64, gA + (size_t)i * 32 * 1024 + kt);
        #pragma unroll
        for (int i = 0; i < 2; ++i)
            glds16(Bs[par] + (i * 32 + w * 8) * 64, gB + (size_t)i * 32 * 1024 + kt);
    };

    f32x4 acc[4][2] = {};
    stage(0, 0);
    stage(1, 64);
    // outstanding: 12. steady state: wait(6) -> tile i landed, tile i+1 in flight.
    #pragma unroll 1
    for (int i = 0; i < 16; ++i) {
        const int cur = i & 1;
        if (i < 15) { WAIT_VM6(); } else { WAIT_VM0(); }
        BAR();
        #pragma unroll
        for (int kh = 0; kh < 2; ++kh) {
            const int ch = (kh * 4 + quad);
            short8 af[4], bf[2];
            #pragma unroll
            for (int rs = 0; rs < 4; ++rs)
                af[rs] = *(const short8*)(As[cur] + (arow + rs * 16) * 64 + (ch ^ cx) * 8);
            #pragma unroll
            for (int cs = 0; cs < 2; ++cs)
                bf[cs] = *(const short8*)(Bs[cur] + (brow + cs * 16) * 64 + (ch ^ cx) * 8);
            #pragma unroll
            for (int rs = 0; rs < 4; ++rs)
                #pragma unroll
                for (int cs = 0; cs < 2; ++cs)
                    acc[rs][cs] = __builtin_amdgcn_mfma_f32_16x16x32_bf16(
                        af[rs], bf[cs], acc[rs][cs], 0, 0, 0);
        }
        BAR();                       // all waves done reading buf cur
        if (i < 14) stage(cur, (i + 2) * 64);
    }

    const int nb = n0 + (w & 1) * 32;
    float bb[2];
    #pragma unroll
    for (int cs = 0; cs < 2; ++cs) bb[cs] = bo[nb + cs * 16 + c];

    #pragma unroll
    for (int rs = 0; rs < 4; ++rs) {
        #pragma unroll
        for (int r = 0; r < 4; ++r) {
            const int row = m0 + (w >> 1) * 64 + rs * 16 + quad * 4 + r;
            float* orow = out + (size_t)row * 1024 + nb;
            #pragma unroll
            for (int cs = 0; cs < 2; ++cs)
                orow[cs * 16 + c] = acc[rs][cs][r] + bb[cs];
        }
    }
}

// ---------------------------------------------------------------------------
// MFMA flash attention v9: merge the 2 co-resident 4-wave blocks of v8 into
// ONE 8-wave block (512 thr) sharing a single K/V staging stream. Per CU per
// tile-iter this halves glds LDS-write traffic (16 KB vs 2x16 KB) and the L2
// KV fetch, with per-wave work (32 q-rows) and TLP (2 waves/SIMD) unchanged.
// Grid 256 = 1 block/CU, 32/XCD. Stage = 2 glds16/thread -> steady vmcnt(2).
// Loop body, swizzles, P layout, epilogue: v8-verbatim (absmax invariant).
// ---------------------------------------------------------------------------
__global__ __launch_bounds__(512) void attn_mfma(
    const u16* __restrict__ qws, const u16* __restrict__ kws,
    const u16* __restrict__ vtws, u16* __restrict__ multi,
    float* __restrict__ resid)
{
    __shared__ u16 Ks[2][64 * 64];     // [par][key][dim], chunk-swizzled (16 KB)
    __shared__ u16 Vs[2][64 * 64];     // [par][dim][key], chunk-swizzled (16 KB)
    __shared__ u16 Ps[8][16 * 64];     // per-wave P [16][64], chunk-XOR swizzled (16 KB)
    const int t = threadIdx.x;
    const int wave = t >> 6, lane = t & 63;
    const int quad = lane >> 4, c = lane & 15;
    const int cx = c & 7;
    const int f = blockIdx.x;                  // 256 blocks (1/CU)
    const int xcd = f & 7, j = f >> 3;         // j 0..31
    const int bh = xcd * 8 + (j & 7);          // 8 heads per XCD (KV L2-resident)
    const int qt = j >> 3;                     // 0..3
    const int b = bh >> 4, h = bh & 15;
    const int q0 = qt * 256 + wave * 32;       // 8 waves x 32 q-rows = 256 rows

    const u16* qb = qws + ((size_t)bh * 1024 + q0) * 64;
    const u16* kb = kws + (size_t)bh * 65536;
    const u16* vb = vtws + (size_t)bh * 65536;

    // Q fragments for 2 row-blocks (rows rb*16 + c), k-halves 0/1
    short8 qa[2][2];
    #pragma unroll
    for (int rb = 0; rb < 2; ++rb) {
        qa[rb][0] = *(const short8*)(qb + (size_t)(rb * 16 + c) * 64 + quad * 8);
        qa[rb][1] = *(const short8*)(qb + (size_t)(rb * 16 + c) * 64 + 32 + quad * 8);
    }

    // staging: 512 thr cover all 64 rows; wave w writes rows w*8..w*8+7
    const int srow = t >> 3;                   // 0..63
    const int gch = (lane & 7) ^ ((lane >> 3) & 7);
    const u16* gK0 = kb + (size_t)srow * 64 + gch * 8;
    const u16* gV0 = vb + (size_t)srow * 1024 + gch * 8;

    // 2 glds16 per stage -> vmcnt +2; steady-state outstanding = 4 (2 tiles)
    auto stage = [&](int par, int kt) {
        glds16(Ks[par] + (wave * 8) * 64, gK0 + (size_t)kt * 64);
        glds16(Vs[par] + (wave * 8) * 64, gV0 + kt);
    };

    f32x4 O[2][4] = {};                // [rb][nt]
    float ps[2][4] = {};               // [rb][r]
    u16* pw = &Ps[wave][0];

    stage(0, 0);
    stage(1, 64);

    #pragma unroll 1
    for (int i = 0; i < 16; ++i) {
        const int cur = i & 1;
        if (i < 15) { WAIT_VM2(); } else { WAIT_VM0(); }  // tile i landed
        BAR();

        const u16* Kc = Ks[cur];
        const u16* Vc = Vs[cur];

        // hoist K/V fragments once per tile; reused by both row-blocks
        short8 kf[4][2], vf[4][2];
        #pragma unroll
        for (int nt = 0; nt < 4; ++nt) {
            const u16* kr = Kc + (nt * 16 + c) * 64;
            kf[nt][0] = *(const short8*)(kr + ((quad ^ cx)) * 8);
            kf[nt][1] = *(const short8*)(kr + (((4 + quad) ^ cx)) * 8);
            const u16* vr = Vc + (nt * 16 + c) * 64;
            vf[nt][0] = *(const short8*)(vr + ((quad ^ cx)) * 8);
            vf[nt][1] = *(const short8*)(vr + (((4 + quad) ^ cx)) * 8);
        }

        #pragma unroll
        for (int rb = 0; rb < 2; ++rb) {
            f32x4 s[4];
            __builtin_amdgcn_s_setprio(1);
            #pragma unroll
            for (int nt = 0; nt < 4; ++nt) {
                f32x4 z = {};
                z = __builtin_amdgcn_mfma_f32_16x16x32_bf16(qa[rb][0], kf[nt][0], z, 0, 0, 0);
                z = __builtin_amdgcn_mfma_f32_16x16x32_bf16(qa[rb][1], kf[nt][1], z, 0, 0, 0);
                s[nt] = z;
            }
            __builtin_amdgcn_s_setprio(0);

            // P store: row prow = quad*4+r, col = nt*16+c; chunk' = chunk ^ (prow&7)
            #pragma unroll
            for (int nt = 0; nt < 4; ++nt)
                #pragma unroll
                for (int r = 0; r < 4; ++r) {
                    float p = __expf(s[nt][r]);
                    ps[rb][r] += p;
                    const int prow = quad * 4 + r;
                    pw[prow * 64 + (((nt * 2 + (c >> 3)) ^ (prow & 7)) * 8) + (c & 7)]
                        = (u16)(__float_as_uint(p) >> 16);
                }
            short8 pa0 = *(const short8*)(pw + c * 64 + ((quad ^ cx)) * 8);
            short8 pa1 = *(const short8*)(pw + c * 64 + (((4 + quad) ^ cx)) * 8);

            __builtin_amdgcn_s_setprio(1);
            #pragma unroll
            for (int nt = 0; nt < 4; ++nt) {
                O[rb][nt] = __builtin_amdgcn_mfma_f32_16x16x32_bf16(pa0, vf[nt][0], O[rb][nt], 0, 0, 0);
                O[rb][nt] = __builtin_amdgcn_mfma_f32_16x16x32_bf16(pa1, vf[nt][1], O[rb][nt], 0, 0, 0);
            }
            __builtin_amdgcn_s_setprio(0);
        }

        BAR();                         // all waves done reading buf cur
        if (i < 14) stage(cur, (i + 2) * 64);
    }

    #pragma unroll
    for (int rb = 0; rb < 2; ++rb) {
        float inv[4];
        #pragma unroll
        for (int r = 0; r < 4; ++r) {
            float sum = ps[rb][r];
            sum += __shfl_xor(sum, 1);
            sum += __shfl_xor(sum, 2);
            sum += __shfl_xor(sum, 4);
            sum += __shfl_xor(sum, 8);
            inv[r] = 1.0f / sum;
        }
        u16* ob = multi + ((size_t)b * 1024 + q0 + rb * 16 + quad * 4) * 1024 + h * 64 + c;
        #pragma unroll
        for (int r = 0; r < 4; ++r) {
            u16* orow = ob + (size_t)r * 1024;
            orow[0]  = f2bf(O[rb][0][r] * inv[r]);
            orow[16] = f2bf(O[rb][1][r] * inv[r]);
            orow[32] = f2bf(O[rb][2][r] * inv[r]);
            orow[48] = f2bf(O[rb][3][r] * inv[r]);
        }

        // resid epilogue: lane holds Q[q0+rb*16+c][quad*8..] in qa[rb] (scaled 1/8)
        float* rr = resid + ((size_t)b * 1024 + q0 + rb * 16 + c) * 1024 + h * 64;
        #pragma unroll
        for (int jj = 0; jj < 8; ++jj) {
            rr[quad * 8 + jj]      = bf2f((u16)qa[rb][0][jj]) * 8.0f;
            rr[32 + quad * 8 + jj] = bf2f((u16)qa[rb][1][jj]) * 8.0f;
        }
    }
}

extern "C" void kernel_launch(void* const* d_in, const int* in_sizes, int n_in,
                              void* d_out, int out_size, void* d_ws, size_t ws_size,
                              hipStream_t stream) {
    const float* queries = (const float*)d_in[0];
    const float* context = (const float*)d_in[1];
    const float* Wq = (const float*)d_in[2];
    const float* bq = (const float*)d_in[3];
    const float* Wk = (const float*)d_in[4];
    const float* bk = (const float*)d_in[5];
    const float* Wv = (const float*)d_in[6];
    const float* bv = (const float*)d_in[7];
    const float* Wo = (const float*)d_in[8];
    const float* bo = (const float*)d_in[9];

    float* out = (float*)d_out;                     // [4,1024,1024] f32
    float* resid = out + (size_t)4 * 1024 * 1024;   // [4,1024,1024] f32

    const size_t M1 = 1024 * 1024;
    u16* Aq   = (u16*)d_ws;          // 4M
    u16* Ac   = Aq + 4 * M1;         // 4M
    u16* Wqt  = Ac + 4 * M1;         // 1M
    u16* Wkt  = Wqt + M1;            // 1M
    u16* Wvt  = Wkt + M1;            // 1M
    u16* Wot  = Wvt + M1;            // 1M
    u16* qws  = Wot + M1;            // 4M (pre-scaled 0.125)
    u16* kws  = qws + 4 * M1;        // 4M
    u16* vtws = kws + 4 * M1;        // 4M [B,H,64,1024]
    u16* mws  = vtws + 4 * M1;       // 4M [B,1024,1024]

    prep<<<5120, 256, 0, stream>>>(queries, context, Wq, Wk, Wv, Wo,
                                   Aq, Ac, Wqt, Wkt, Wvt, Wot);
    gemm_qkv3<<<768, 256, 0, stream>>>(Aq, Ac, Wqt, Wkt, Wvt,
                                       bq, bk, bv, qws, kws, vtws);
    attn_mfma<<<256, 512, 0, stream>>>(qws, kws, vtws, mws, resid);
    gemm_out<<<512, 256, 0, stream>>>(mws, Wot, bo, out);
}

// Round 9
// 188.965 us; speedup vs baseline: 1.0151x; 1.0094x over previous
//
#include <hip/hip_runtime.h>
#include <hip/hip_bf16.h>

// Shapes: B=4, LQ=LKV=1024, D=1024, H=16, HD=64, N=H*HD=1024, M=B*LQ=4096
// ws (u16, 56 MB): Aq 4M | Ac 4M | Wqt 1M | Wkt 1M | Wvt 1M | Wot 1M |
//                  qws 4M (x0.125) | kws 4M | vtws 4M (dim-major) | mws 4M

typedef unsigned short u16;
typedef __attribute__((ext_vector_type(8))) short short8;   // 8 bf16 = 4 VGPRs
typedef __attribute__((ext_vector_type(4))) float f32x4;

__device__ __forceinline__ float bf2f(u16 u) {
    union { unsigned int i; float f; } c;
    c.i = ((unsigned int)u) << 16;
    return c.f;
}

__device__ __forceinline__ u16 f2bf(float f) {
    unsigned int x = __float_as_uint(f);
    unsigned int r = (x + 0x7fffu + ((x >> 16) & 1u)) >> 16;  // RNE
    return (u16)r;
}

// async global->LDS, 16B/lane; lds base MUST be wave-uniform (HW adds lane*16)
__device__ __forceinline__ void glds16(u16* lds, const u16* g) {
    __builtin_amdgcn_global_load_lds(
        (const __attribute__((address_space(1))) void*)g,
        (__attribute__((address_space(3))) void*)lds, 16, 0, 0);
}

// raw-barrier discipline (no __syncthreads in pipelined loops: it drains vmcnt)
#define FENCE() asm volatile("" ::: "memory")
#define BAR() do { FENCE(); __builtin_amdgcn_s_barrier(); FENCE(); } while (0)
#define WAIT_VM8() do { asm volatile("s_waitcnt vmcnt(8)" ::: "memory"); \
                        __builtin_amdgcn_sched_barrier(0); } while (0)
#define WAIT_VM6() do { asm volatile("s_waitcnt vmcnt(6)" ::: "memory"); \
                        __builtin_amdgcn_sched_barrier(0); } while (0)
#define WAIT_VM4() do { asm volatile("s_waitcnt vmcnt(4)" ::: "memory"); \
                        __builtin_amdgcn_sched_barrier(0); } while (0)
#define WAIT_VM0() do { asm volatile("s_waitcnt vmcnt(0)" ::: "memory"); \
                        __builtin_amdgcn_sched_barrier(0); } while (0)

// ---------------------------------------------------------------------------
// Fused pre-pass, flat grid 5120 blocks x 256 thr (unchanged)
// ---------------------------------------------------------------------------
__global__ __launch_bounds__(256) void prep(
    const float* __restrict__ q, const float* __restrict__ ctx,
    const float* __restrict__ Wq, const float* __restrict__ Wk,
    const float* __restrict__ Wv, const float* __restrict__ Wo,
    u16* __restrict__ Aq, u16* __restrict__ Ac,
    u16* __restrict__ Wqt, u16* __restrict__ Wkt,
    u16* __restrict__ Wvt, u16* __restrict__ Wot)
{
    __shared__ float ls[64][65];
    const int t = threadIdx.x;
    int bid = blockIdx.x;

    if (bid < 4096) {
        const float* in = (bid < 2048) ? q : ctx;
        u16* out = (bid < 2048) ? Aq : Ac;
        size_t i = ((size_t)(bid & 2047) * 256 + t) * 8;
        float4 v0 = *(const float4*)(in + i);
        float4 v1 = *(const float4*)(in + i + 4);
        short8 p;
        p[0] = (short)f2bf(v0.x); p[1] = (short)f2bf(v0.y);
        p[2] = (short)f2bf(v0.z); p[3] = (short)f2bf(v0.w);
        p[4] = (short)f2bf(v1.x); p[5] = (short)f2bf(v1.y);
        p[6] = (short)f2bf(v1.z); p[7] = (short)f2bf(v1.w);
        *(short8*)(out + i) = p;
        return;
    }
    bid -= 4096;
    const float* in; u16* out; int C; size_t moff; int rt, ct;
    if (bid < 768) {
        const int m = bid >> 8, idx = bid & 255;
        in = (m == 0) ? Wq : (m == 1) ? Wk : Wv;
        out = (m == 0) ? Wqt : (m == 1) ? Wkt : Wvt;
        C = 64; rt = (idx & 15) * 64; ct = 0; moff = (size_t)(idx >> 4) * 65536;
    } else {
        const int idx = bid - 768;
        in = Wo; out = Wot; C = 1024; moff = 0;
        rt = (idx & 15) * 64; ct = (idx >> 4) * 64;
    }
    #pragma unroll
    for (int i = 0; i < 4; ++i) {
        int s = i * 256 + t;
        int row = s >> 4, chunk = s & 15;
        float4 v = *(const float4*)(in + moff + (size_t)(rt + row) * C + ct + chunk * 4);
        ls[row][chunk * 4 + 0] = v.x;
        ls[row][chunk * 4 + 1] = v.y;
        ls[row][chunk * 4 + 2] = v.z;
        ls[row][chunk * 4 + 3] = v.w;
    }
    __syncthreads();
    #pragma unroll
    for (int i = 0; i < 2; ++i) {
        int s = i * 256 + t;
        int n = s >> 3, kc = s & 7;
        short8 p;
        #pragma unroll
        for (int j = 0; j < 8; ++j) p[j] = (short)f2bf(ls[kc * 8 + j][n]);
        *(short8*)(out + moff + (size_t)(ct + n) * 1024 + rt + kc * 8) = p;
    }
}

// ---------------------------------------------------------------------------
// Q/K/V projection v5 (gemm_qkv2): 256x256 tile, BK=64, 2-phase counted dbuf
// (best-measured-total config, R5). This round: z==2 (V) epilogue rewritten
// as an LDS-bounce — direct ushort4 stores to vtws[hd][l] touched 64 distinct
// cache lines per wave-instr (lane c -> hd -> stride 1024 u16), 4x the L2
// segment traffic of the z<2 path, making V blocks the stragglers. Bounce:
// wave-private [64 hd][128 l] u16 region in the (post-loop free) 128 KB lds,
// XOR-swizzled (<=2-way bank), then contiguous 256 B short8 row stores.
// Same values, same rounding (absmax invariant).
// ---------------------------------------------------------------------------
__global__ __launch_bounds__(512) void gemm_qkv2(
    const u16* __restrict__ Aq, const u16* __restrict__ Ac,
    const u16* __restrict__ Wqt, const u16* __restrict__ Wkt,
    const u16* __restrict__ Wvt,
    const float* __restrict__ bq, const float* __restrict__ bk,
    const float* __restrict__ bv,
    u16* __restrict__ qws, u16* __restrict__ kws, u16* __restrict__ vtws)
{
    __shared__ u16 lds[2][2][256 * 64];   // [parity][0=A,1=B][row][k]  128 KB

    const int tid = threadIdx.x;
    const int w = tid >> 6, lane = tid & 63;
    const int wr = w >> 2, wc = w & 3;                 // 2 x 4 wave grid
    const int quad = lane >> 4, c = lane & 15, cx = c & 7;
    const int sr = tid >> 3;                           // staging row (0..63)
    const int gch = (tid & 7) ^ (sr & 7);              // source-side swizzle

    // 192 blocks: xcd owns 2 mtiles x 4 nt x 3 z (24 blocks, all co-resident)
    const int f = blockIdx.x;
    const int xcd = f & 7, r = f >> 3;                 // r 0..23
    const int z = r >> 3;                              // 0..2
    const int mt = xcd * 2 + ((r >> 2) & 1);           // 0..15
    const int nt = r & 3;                              // 0..3
    const int m0 = mt * 256, n0 = nt * 256;

    const u16* A = (z == 0) ? Aq : Ac;
    const u16* Wt = (z == 0) ? Wqt : (z == 1) ? Wkt : Wvt;
    const float* bias = (z == 0) ? bq : (z == 1) ? bk : bv;

    const u16* gAt = A + (size_t)(m0 + sr) * 1024 + gch * 8;
    const u16* gBt = Wt + (size_t)(n0 + sr) * 1024 + gch * 8;

    // one full 256-row A tile + 256-row B tile: 8 glds16 per thread
    auto stage = [&](int par, int t) {
        #pragma unroll
        for (int i = 0; i < 4; ++i) {
            glds16(&lds[par][0][(i * 64 + w * 8) * 64],
                   gAt + (size_t)(i * 64) * 1024 + t * 64);
            glds16(&lds[par][1][(i * 64 + w * 8) * 64],
                   gBt + (size_t)(i * 64) * 1024 + t * 64);
        }
    };

    f32x4 acc[8][4] = {};          // [mh*4+mf][nh*2+nf]
    short8 aq[4][2], bA[2][2], bB[2][2];

    auto ldA = [&](int par, int mh) {
        #pragma unroll
        for (int mf = 0; mf < 4; ++mf)
            #pragma unroll
            for (int ks = 0; ks < 2; ++ks)
                aq[mf][ks] = *(const short8*)&lds[par][0][
                    (wr * 128 + mh * 64 + mf * 16 + c) * 64 + (((ks * 4 + quad) ^ cx) * 8)];
    };
    auto ldB = [&](int par, int nh, short8 (&bq_)[2][2]) {
        #pragma unroll
        for (int nf = 0; nf < 2; ++nf)
            #pragma unroll
            for (int ks = 0; ks < 2; ++ks)
                bq_[nf][ks] = *(const short8*)&lds[par][1][
                    (wc * 64 + nh * 32 + nf * 16 + c) * 64 + (((ks * 4 + quad) ^ cx) * 8)];
    };
    auto mma = [&](int mh, int nh, short8 (&bq_)[2][2]) {
        #pragma unroll
        for (int mf = 0; mf < 4; ++mf)
            #pragma unroll
            for (int nf = 0; nf < 2; ++nf)
                #pragma unroll
                for (int ks = 0; ks < 2; ++ks)
                    acc[mh * 4 + mf][nh * 2 + nf] =
                        __builtin_amdgcn_mfma_f32_16x16x32_bf16(
                            aq[mf][ks], bq_[nf][ks], acc[mh * 4 + mf][nh * 2 + nf], 0, 0, 0);
    };

    stage(0, 0);
    stage(1, 1);
    // outstanding: 16. steady state: wait(8) -> tile i landed, tile i+1 in flight.
    #pragma unroll 1
    for (int i = 0; i < 16; ++i) {
        const int cur = i & 1;
        if (i < 15) { WAIT_VM8(); } else { WAIT_VM0(); }
        BAR();
        // quadrant order with fragment reuse; compiler schedules ds_reads freely
        ldA(cur, 0);
        ldB(cur, 0, bA);
        mma(0, 0, bA);
        ldB(cur, 1, bB);
        mma(0, 1, bB);
        ldA(cur, 1);
        mma(1, 1, bB);
        mma(1, 0, bA);
        BAR();                       // all waves done reading buf cur
        if (i < 14) stage(cur, i + 2);
    }

    // ---- epilogue ----
    const int h = nt * 4 + wc;                 // wave wc owns one head
    const int b = m0 >> 10;                    // 256-row tile never crosses batch
    const int lbase = (m0 & 1023) + wr * 128;

    float bb[4];
    #pragma unroll
    for (int cn = 0; cn < 4; ++cn)
        bb[cn] = bias[h * 64 + (cn >> 1) * 32 + (cn & 1) * 16 + c];

    if (z < 2) {
        u16* dst = (z == 0) ? qws : kws;
        const float scale = (z == 0) ? 0.125f : 1.0f;
        u16* dbase = dst + (size_t)(b * 16 + h) * 1024 * 64;
        #pragma unroll
        for (int mi = 0; mi < 8; ++mi) {
            const int ro = (mi >> 2) * 64 + (mi & 3) * 16;
            const int rowb = lbase + ro + quad * 4;
            #pragma unroll
            for (int rr = 0; rr < 4; ++rr) {
                u16* drow = dbase + (size_t)(rowb + rr) * 64;
                #pragma unroll
                for (int cn = 0; cn < 4; ++cn) {
                    const int hd = (cn >> 1) * 32 + (cn & 1) * 16 + c;
                    drow[hd] = f2bf((acc[mi][cn][rr] + bb[cn]) * scale);
                }
            }
        }
    } else {
        // V epilogue via LDS-bounce (lds is free after the K-loop's final BAR).
        // Wave-private region: [64 hd][128 l] u16 = 16 KB at lw = lds + w*8192.
        // Swizzle: u16 idx = hd*128 + (l4 ^ ((hd&15)<<3)); XOR is a multiple of
        // 8 u16 so ushort4 (l%4==0) and short8 (l%8==0) accesses stay intact;
        // write: lanes c/c+8 alias -> 2-way (free); read: 16 lanes span 128 u16.
        u16* lw = &lds[0][0][0] + w * 8192;
        #pragma unroll
        for (int mi = 0; mi < 8; ++mi) {
            const int ll = (mi >> 2) * 64 + (mi & 3) * 16 + quad * 4;
            #pragma unroll
            for (int cn = 0; cn < 4; ++cn) {
                const int hd = (cn >> 1) * 32 + (cn & 1) * 16 + c;
                ushort4 pk;
                pk.x = f2bf(acc[mi][cn][0] + bb[cn]);
                pk.y = f2bf(acc[mi][cn][1] + bb[cn]);
                pk.z = f2bf(acc[mi][cn][2] + bb[cn]);
                pk.w = f2bf(acc[mi][cn][3] + bb[cn]);
                *(ushort4*)(lw + hd * 128 + (ll ^ ((hd & 15) << 3))) = pk;
            }
        }
        // No cross-wave sharing: each wave reads only its own region, so no
        // barrier needed; compiler orders the ds_write -> ds_read dependency.
        u16* dbase = vtws + (size_t)(b * 16 + h) * 64 * 1024;
        #pragma unroll
        for (int it = 0; it < 16; ++it) {
            const int s = it * 64 + lane;      // 0..1023 = 64 hd x 16 chunks
            const int hd = s >> 4, ck = s & 15;
            short8 v = *(const short8*)(lw + hd * 128 + ((ck * 8) ^ ((hd & 15) << 3)));
            *(short8*)(dbase + (size_t)hd * 1024 + lbase + ck * 8) = v;
        }
    }
}

// ---------------------------------------------------------------------------
// Output projection v4: 2-phase counted pipeline (unchanged this round)
// ---------------------------------------------------------------------------
__global__ __launch_bounds__(256) void gemm_out(
    const u16* __restrict__ A, const u16* __restrict__ Wot,
    const float* __restrict__ bo, float* __restrict__ out)
{
    __shared__ u16 As[2][128 * 64];   // 32 KB
    __shared__ u16 Bs[2][64 * 64];    // 16 KB
    const int f = blockIdx.x;
    const int xcd = f & 7, k = f >> 3;
    const int m0 = (xcd * 4 + (k & 3)) * 128;
    const int n0 = (k >> 2) * 64;
    const int t = threadIdx.x;
    const int w = t >> 6, lane = t & 63;
    const int quad = lane >> 4, c = lane & 15;
    const int cx = c & 7;

    const int sr = w * 8 + (lane >> 3);
    const int gch = (lane & 7) ^ ((lane >> 3) & 7);
    const u16* gA = A + (size_t)(m0 + sr) * 1024 + gch * 8;
    const u16* gB = Wot + (size_t)(n0 + sr) * 1024 + gch * 8;

    const int arow = (w >> 1) * 64 + c;
    const int brow = (w & 1) * 32 + c;

    auto stage = [&](int par, int kt) {        // 6 glds16 per thread
        #pragma unroll
        for (int i = 0; i < 4; ++i)
            glds16(As[par] + (i * 32 + w * 8) * 64, gA + (size_t)i * 32 * 1024 + kt);
        #pragma unroll
        for (int i = 0; i < 2; ++i)
            glds16(Bs[par] + (i * 32 + w * 8) * 64, gB + (size_t)i * 32 * 1024 + kt);
    };

    f32x4 acc[4][2] = {};
    stage(0, 0);
    stage(1, 64);
    // outstanding: 12. steady state: wait(6) -> tile i landed, tile i+1 in flight.
    #pragma unroll 1
    for (int i = 0; i < 16; ++i) {
        const int cur = i & 1;
        if (i < 15) { WAIT_VM6(); } else { WAIT_VM0(); }
        BAR();
        #pragma unroll
        for (int kh = 0; kh < 2; ++kh) {
            const int ch = (kh * 4 + quad);
            short8 af[4], bf[2];
            #pragma unroll
            for (int rs = 0; rs < 4; ++rs)
                af[rs] = *(const short8*)(As[cur] + (arow + rs * 16) * 64 + (ch ^ cx) * 8);
            #pragma unroll
            for (int cs = 0; cs < 2; ++cs)
                bf[cs] = *(const short8*)(Bs[cur] + (brow + cs * 16) * 64 + (ch ^ cx) * 8);
            #pragma unroll
            for (int rs = 0; rs < 4; ++rs)
                #pragma unroll
                for (int cs = 0; cs < 2; ++cs)
                    acc[rs][cs] = __builtin_amdgcn_mfma_f32_16x16x32_bf16(
                        af[rs], bf[cs], acc[rs][cs], 0, 0, 0);
        }
        BAR();                       // all waves done reading buf cur
        if (i < 14) stage(cur, (i + 2) * 64);
    }

    const int nb = n0 + (w & 1) * 32;
    float bb[2];
    #pragma unroll
    for (int cs = 0; cs < 2; ++cs) bb[cs] = bo[nb + cs * 16 + c];

    #pragma unroll
    for (int rs = 0; rs < 4; ++rs) {
        #pragma unroll
        for (int r = 0; r < 4; ++r) {
            const int row = m0 + (w >> 1) * 64 + rs * 16 + quad * 4 + r;
            float* orow = out + (size_t)row * 1024 + nb;
            #pragma unroll
            for (int cs = 0; cs < 2; ++cs)
                orow[cs * 16 + c] = acc[rs][cs][r] + bb[cs];
        }
    }
}

// ---------------------------------------------------------------------------
// MFMA flash attention v8 (restored — best-measured attn config): 32 q-rows
// per wave, grid 512 x 256 thr (2 blocks/CU), dbuf + counted vmcnt(4).
// v9's 1-block/CU merge was directionally worse (barrier convoy > traffic).
// ---------------------------------------------------------------------------
__global__ __launch_bounds__(256) void attn_mfma(
    const u16* __restrict__ qws, const u16* __restrict__ kws,
    const u16* __restrict__ vtws, u16* __restrict__ multi,
    float* __restrict__ resid)
{
    __shared__ u16 Ks[2][64 * 64];     // [par][key][dim], chunk-swizzled (16 KB)
    __shared__ u16 Vs[2][64 * 64];     // [par][dim][key], chunk-swizzled (16 KB)
    __shared__ u16 Ps[4][16 * 64];     // per-wave P [16][64], chunk-XOR swizzled (8 KB)
    const int t = threadIdx.x;
    const int wave = t >> 6, lane = t & 63;
    const int quad = lane >> 4, c = lane & 15;
    const int cx = c & 7;
    const int f = blockIdx.x;                  // 512 blocks
    const int xcd = f & 7, j = f >> 3;         // j 0..63
    const int bh = xcd * 8 + (j & 7);          // 8 heads per XCD (KV L2-resident)
    const int qt = j >> 3;                     // 0..7
    const int b = bh >> 4, h = bh & 15;
    const int q0 = qt * 128 + wave * 32;       // 32 q-rows per wave

    const u16* qb = qws + ((size_t)bh * 1024 + q0) * 64;
    const u16* kb = kws + (size_t)bh * 65536;
    const u16* vb = vtws + (size_t)bh * 65536;

    // Q fragments for 2 row-blocks (rows rb*16 + c), k-halves 0/1
    short8 qa[2][2];
    #pragma unroll
    for (int rb = 0; rb < 2; ++rb) {
        qa[rb][0] = *(const short8*)(qb + (size_t)(rb * 16 + c) * 64 + quad * 8);
        qa[rb][1] = *(const short8*)(qb + (size_t)(rb * 16 + c) * 64 + 32 + quad * 8);
    }

    const int srow = wave * 16 + (lane >> 3);
    const int gch = (lane & 7) ^ ((lane >> 3) & 7);
    const u16* gK0 = kb + (size_t)srow * 64 + gch * 8;
    const u16* gK1 = kb + (size_t)(srow + 8) * 64 + gch * 8;
    const u16* gV0 = vb + (size_t)srow * 1024 + gch * 8;
    const u16* gV1 = vb + (size_t)(srow + 8) * 1024 + gch * 8;

    // 4 glds16 per stage -> vmcnt +4; steady-state outstanding = 8 (2 tiles)
    auto stage = [&](int par, int kt) {
        glds16(Ks[par] + (wave * 16) * 64,     gK0 + (size_t)kt * 64);
        glds16(Ks[par] + (wave * 16 + 8) * 64, gK1 + (size_t)kt * 64);
        glds16(Vs[par] + (wave * 16) * 64,     gV0 + kt);
        glds16(Vs[par] + (wave * 16 + 8) * 64, gV1 + kt);
    };

    f32x4 O[2][4] = {};                // [rb][nt]
    float ps[2][4] = {};               // [rb][r]
    u16* pw = &Ps[wave][0];

    stage(0, 0);
    stage(1, 64);

    #pragma unroll 1
    for (int i = 0; i < 16; ++i) {
        const int cur = i & 1;
        if (i < 15) { WAIT_VM4(); } else { WAIT_VM0(); }  // tile i landed
        BAR();

        const u16* Kc = Ks[cur];
        const u16* Vc = Vs[cur];

        // hoist K/V fragments once per tile; reused by both row-blocks
        short8 kf[4][2], vf[4][2];
        #pragma unroll
        for (int nt = 0; nt < 4; ++nt) {
            const u16* kr = Kc + (nt * 16 + c) * 64;
            kf[nt][0] = *(const short8*)(kr + ((quad ^ cx)) * 8);
            kf[nt][1] = *(const short8*)(kr + (((4 + quad) ^ cx)) * 8);
            const u16* vr = Vc + (nt * 16 + c) * 64;
            vf[nt][0] = *(const short8*)(vr + ((quad ^ cx)) * 8);
            vf[nt][1] = *(const short8*)(vr + (((4 + quad) ^ cx)) * 8);
        }

        #pragma unroll
        for (int rb = 0; rb < 2; ++rb) {
            f32x4 s[4];
            __builtin_amdgcn_s_setprio(1);
            #pragma unroll
            for (int nt = 0; nt < 4; ++nt) {
                f32x4 z = {};
                z = __builtin_amdgcn_mfma_f32_16x16x32_bf16(qa[rb][0], kf[nt][0], z, 0, 0, 0);
                z = __builtin_amdgcn_mfma_f32_16x16x32_bf16(qa[rb][1], kf[nt][1], z, 0, 0, 0);
                s[nt] = z;
            }
            __builtin_amdgcn_s_setprio(0);

            // P store: row prow = quad*4+r, col = nt*16+c; chunk' = chunk ^ (prow&7)
            #pragma unroll
            for (int nt = 0; nt < 4; ++nt)
                #pragma unroll
                for (int r = 0; r < 4; ++r) {
                    float p = __expf(s[nt][r]);
                    ps[rb][r] += p;
                    const int prow = quad * 4 + r;
                    pw[prow * 64 + (((nt * 2 + (c >> 3)) ^ (prow & 7)) * 8) + (c & 7)]
                        = (u16)(__float_as_uint(p) >> 16);
                }
            short8 pa0 = *(const short8*)(pw + c * 64 + ((quad ^ cx)) * 8);
            short8 pa1 = *(const short8*)(pw + c * 64 + (((4 + quad) ^ cx)) * 8);

            __builtin_amdgcn_s_setprio(1);
            #pragma unroll
            for (int nt = 0; nt < 4; ++nt) {
                O[rb][nt] = __builtin_amdgcn_mfma_f32_16x16x32_bf16(pa0, vf[nt][0], O[rb][nt], 0, 0, 0);
                O[rb][nt] = __builtin_amdgcn_mfma_f32_16x16x32_bf16(pa1, vf[nt][1], O[rb][nt], 0, 0, 0);
            }
            __builtin_amdgcn_s_setprio(0);
        }

        BAR();                         // all waves done reading buf cur
        if (i < 14) stage(cur, (i + 2) * 64);
    }

    #pragma unroll
    for (int rb = 0; rb < 2; ++rb) {
        float inv[4];
        #pragma unroll
        for (int r = 0; r < 4; ++r) {
            float sum = ps[rb][r];
            sum += __shfl_xor(sum, 1);
            sum += __shfl_xor(sum, 2);
            sum += __shfl_xor(sum, 4);
            sum += __shfl_xor(sum, 8);
            inv[r] = 1.0f / sum;
        }
        u16* ob = multi + ((size_t)b * 1024 + q0 + rb * 16 + quad * 4) * 1024 + h * 64 + c;
        #pragma unroll
        for (int r = 0; r < 4; ++r) {
            u16* orow = ob + (size_t)r * 1024;
            orow[0]  = f2bf(O[rb][0][r] * inv[r]);
            orow[16] = f2bf(O[rb][1][r] * inv[r]);
            orow[32] = f2bf(O[rb][2][r] * inv[r]);
            orow[48] = f2bf(O[rb][3][r] * inv[r]);
        }

        // resid epilogue: lane holds Q[q0+rb*16+c][quad*8..] in qa[rb] (scaled 1/8)
        float* rr = resid + ((size_t)b * 1024 + q0 + rb * 16 + c) * 1024 + h * 64;
        #pragma unroll
        for (int jj = 0; jj < 8; ++jj) {
            rr[quad * 8 + jj]      = bf2f((u16)qa[rb][0][jj]) * 8.0f;
            rr[32 + quad * 8 + jj] = bf2f((u16)qa[rb][1][jj]) * 8.0f;
        }
    }
}

extern "C" void kernel_launch(void* const* d_in, const int* in_sizes, int n_in,
                              void* d_out, int out_size, void* d_ws, size_t ws_size,
                              hipStream_t stream) {
    const float* queries = (const float*)d_in[0];
    const float* context = (const float*)d_in[1];
    const float* Wq = (const float*)d_in[2];
    const float* bq = (const float*)d_in[3];
    const float* Wk = (const float*)d_in[4];
    const float* bk = (const float*)d_in[5];
    const float* Wv = (const float*)d_in[6];
    const float* bv = (const float*)d_in[7];
    const float* Wo = (const float*)d_in[8];
    const float* bo = (const float*)d_in[9];

    float* out = (float*)d_out;                     // [4,1024,1024] f32
    float* resid = out + (size_t)4 * 1024 * 1024;   // [4,1024,1024] f32

    const size_t M1 = 1024 * 1024;
    u16* Aq   = (u16*)d_ws;          // 4M
    u16* Ac   = Aq + 4 * M1;         // 4M
    u16* Wqt  = Ac + 4 * M1;         // 1M
    u16* Wkt  = Wqt + M1;            // 1M
    u16* Wvt  = Wkt + M1;            // 1M
    u16* Wot  = Wvt + M1;            // 1M
    u16* qws  = Wot + M1;            // 4M (pre-scaled 0.125)
    u16* kws  = qws + 4 * M1;        // 4M
    u16* vtws = kws + 4 * M1;        // 4M [B,H,64,1024]
    u16* mws  = vtws + 4 * M1;       // 4M [B,1024,1024]

    prep<<<5120, 256, 0, stream>>>(queries, context, Wq, Wk, Wv, Wo,
                                   Aq, Ac, Wqt, Wkt, Wvt, Wot);
    gemm_qkv2<<<192, 512, 0, stream>>>(Aq, Ac, Wqt, Wkt, Wvt,
                                       bq, bk, bv, qws, kws, vtws);
    attn_mfma<<<512, 256, 0, stream>>>(qws, kws, vtws, mws, resid);
    gemm_out<<<512, 256, 0, stream>>>(mws, Wot, bo, out);
}

// Round 10
// 184.470 us; speedup vs baseline: 1.0399x; 1.0244x over previous
//
#include <hip/hip_runtime.h>
#include <hip/hip_bf16.h>

// Shapes: B=4, LQ=LKV=1024, D=1024, H=16, HD=64, N=H*HD=1024, M=B*LQ=4096
// ws (u16, 56 MB): Aq 4M | Ac 4M | Wqt 1M | Wkt 1M | Wvt 1M | Wot 1M |
//                  qws 4M (x0.125) | kws 4M | vtws 4M (dim-major) | mws 4M

typedef unsigned short u16;
typedef __attribute__((ext_vector_type(8))) short short8;   // 8 bf16 = 4 VGPRs
typedef __attribute__((ext_vector_type(4))) float f32x4;

__device__ __forceinline__ float bf2f(u16 u) {
    union { unsigned int i; float f; } c;
    c.i = ((unsigned int)u) << 16;
    return c.f;
}

__device__ __forceinline__ u16 f2bf(float f) {
    unsigned int x = __float_as_uint(f);
    unsigned int r = (x + 0x7fffu + ((x >> 16) & 1u)) >> 16;  // RNE
    return (u16)r;
}

// async global->LDS, 16B/lane; lds base MUST be wave-uniform (HW adds lane*16)
__device__ __forceinline__ void glds16(u16* lds, const u16* g) {
    __builtin_amdgcn_global_load_lds(
        (const __attribute__((address_space(1))) void*)g,
        (__attribute__((address_space(3))) void*)lds, 16, 0, 0);
}

// raw-barrier discipline (no __syncthreads in pipelined loops: it drains vmcnt)
#define FENCE() asm volatile("" ::: "memory")
#define BAR() do { FENCE(); __builtin_amdgcn_s_barrier(); FENCE(); } while (0)
#define WAIT_VM8() do { asm volatile("s_waitcnt vmcnt(8)" ::: "memory"); \
                        __builtin_amdgcn_sched_barrier(0); } while (0)
#define WAIT_VM6() do { asm volatile("s_waitcnt vmcnt(6)" ::: "memory"); \
                        __builtin_amdgcn_sched_barrier(0); } while (0)
#define WAIT_VM4() do { asm volatile("s_waitcnt vmcnt(4)" ::: "memory"); \
                        __builtin_amdgcn_sched_barrier(0); } while (0)
#define WAIT_VM0() do { asm volatile("s_waitcnt vmcnt(0)" ::: "memory"); \
                        __builtin_amdgcn_sched_barrier(0); } while (0)

// ---------------------------------------------------------------------------
// Fused pre-pass, flat grid 5120 blocks x 256 thr (unchanged)
// ---------------------------------------------------------------------------
__global__ __launch_bounds__(256) void prep(
    const float* __restrict__ q, const float* __restrict__ ctx,
    const float* __restrict__ Wq, const float* __restrict__ Wk,
    const float* __restrict__ Wv, const float* __restrict__ Wo,
    u16* __restrict__ Aq, u16* __restrict__ Ac,
    u16* __restrict__ Wqt, u16* __restrict__ Wkt,
    u16* __restrict__ Wvt, u16* __restrict__ Wot)
{
    __shared__ float ls[64][65];
    const int t = threadIdx.x;
    int bid = blockIdx.x;

    if (bid < 4096) {
        const float* in = (bid < 2048) ? q : ctx;
        u16* out = (bid < 2048) ? Aq : Ac;
        size_t i = ((size_t)(bid & 2047) * 256 + t) * 8;
        float4 v0 = *(const float4*)(in + i);
        float4 v1 = *(const float4*)(in + i + 4);
        short8 p;
        p[0] = (short)f2bf(v0.x); p[1] = (short)f2bf(v0.y);
        p[2] = (short)f2bf(v0.z); p[3] = (short)f2bf(v0.w);
        p[4] = (short)f2bf(v1.x); p[5] = (short)f2bf(v1.y);
        p[6] = (short)f2bf(v1.z); p[7] = (short)f2bf(v1.w);
        *(short8*)(out + i) = p;
        return;
    }
    bid -= 4096;
    const float* in; u16* out; int C; size_t moff; int rt, ct;
    if (bid < 768) {
        const int m = bid >> 8, idx = bid & 255;
        in = (m == 0) ? Wq : (m == 1) ? Wk : Wv;
        out = (m == 0) ? Wqt : (m == 1) ? Wkt : Wvt;
        C = 64; rt = (idx & 15) * 64; ct = 0; moff = (size_t)(idx >> 4) * 65536;
    } else {
        const int idx = bid - 768;
        in = Wo; out = Wot; C = 1024; moff = 0;
        rt = (idx & 15) * 64; ct = (idx >> 4) * 64;
    }
    #pragma unroll
    for (int i = 0; i < 4; ++i) {
        int s = i * 256 + t;
        int row = s >> 4, chunk = s & 15;
        float4 v = *(const float4*)(in + moff + (size_t)(rt + row) * C + ct + chunk * 4);
        ls[row][chunk * 4 + 0] = v.x;
        ls[row][chunk * 4 + 1] = v.y;
        ls[row][chunk * 4 + 2] = v.z;
        ls[row][chunk * 4 + 3] = v.w;
    }
    __syncthreads();
    #pragma unroll
    for (int i = 0; i < 2; ++i) {
        int s = i * 256 + t;
        int n = s >> 3, kc = s & 7;
        short8 p;
        #pragma unroll
        for (int j = 0; j < 8; ++j) p[j] = (short)f2bf(ls[kc * 8 + j][n]);
        *(short8*)(out + moff + (size_t)(ct + n) * 1024 + rt + kc * 8) = p;
    }
}

// ---------------------------------------------------------------------------
// Q/K/V projection v5 (gemm_qkv2): 256x256 tile, BK=64, 2-phase counted dbuf,
// V epilogue via LDS-bounce. (unchanged this round)
// ---------------------------------------------------------------------------
__global__ __launch_bounds__(512) void gemm_qkv2(
    const u16* __restrict__ Aq, const u16* __restrict__ Ac,
    const u16* __restrict__ Wqt, const u16* __restrict__ Wkt,
    const u16* __restrict__ Wvt,
    const float* __restrict__ bq, const float* __restrict__ bk,
    const float* __restrict__ bv,
    u16* __restrict__ qws, u16* __restrict__ kws, u16* __restrict__ vtws)
{
    __shared__ u16 lds[2][2][256 * 64];   // [parity][0=A,1=B][row][k]  128 KB

    const int tid = threadIdx.x;
    const int w = tid >> 6, lane = tid & 63;
    const int wr = w >> 2, wc = w & 3;                 // 2 x 4 wave grid
    const int quad = lane >> 4, c = lane & 15, cx = c & 7;
    const int sr = tid >> 3;                           // staging row (0..63)
    const int gch = (tid & 7) ^ (sr & 7);              // source-side swizzle

    // 192 blocks: xcd owns 2 mtiles x 4 nt x 3 z (24 blocks, all co-resident)
    const int f = blockIdx.x;
    const int xcd = f & 7, r = f >> 3;                 // r 0..23
    const int z = r >> 3;                              // 0..2
    const int mt = xcd * 2 + ((r >> 2) & 1);           // 0..15
    const int nt = r & 3;                              // 0..3
    const int m0 = mt * 256, n0 = nt * 256;

    const u16* A = (z == 0) ? Aq : Ac;
    const u16* Wt = (z == 0) ? Wqt : (z == 1) ? Wkt : Wvt;
    const float* bias = (z == 0) ? bq : (z == 1) ? bk : bv;

    const u16* gAt = A + (size_t)(m0 + sr) * 1024 + gch * 8;
    const u16* gBt = Wt + (size_t)(n0 + sr) * 1024 + gch * 8;

    // one full 256-row A tile + 256-row B tile: 8 glds16 per thread
    auto stage = [&](int par, int t) {
        #pragma unroll
        for (int i = 0; i < 4; ++i) {
            glds16(&lds[par][0][(i * 64 + w * 8) * 64],
                   gAt + (size_t)(i * 64) * 1024 + t * 64);
            glds16(&lds[par][1][(i * 64 + w * 8) * 64],
                   gBt + (size_t)(i * 64) * 1024 + t * 64);
        }
    };

    f32x4 acc[8][4] = {};          // [mh*4+mf][nh*2+nf]
    short8 aq[4][2], bA[2][2], bB[2][2];

    auto ldA = [&](int par, int mh) {
        #pragma unroll
        for (int mf = 0; mf < 4; ++mf)
            #pragma unroll
            for (int ks = 0; ks < 2; ++ks)
                aq[mf][ks] = *(const short8*)&lds[par][0][
                    (wr * 128 + mh * 64 + mf * 16 + c) * 64 + (((ks * 4 + quad) ^ cx) * 8)];
    };
    auto ldB = [&](int par, int nh, short8 (&bq_)[2][2]) {
        #pragma unroll
        for (int nf = 0; nf < 2; ++nf)
            #pragma unroll
            for (int ks = 0; ks < 2; ++ks)
                bq_[nf][ks] = *(const short8*)&lds[par][1][
                    (wc * 64 + nh * 32 + nf * 16 + c) * 64 + (((ks * 4 + quad) ^ cx) * 8)];
    };
    auto mma = [&](int mh, int nh, short8 (&bq_)[2][2]) {
        #pragma unroll
        for (int mf = 0; mf < 4; ++mf)
            #pragma unroll
            for (int nf = 0; nf < 2; ++nf)
                #pragma unroll
                for (int ks = 0; ks < 2; ++ks)
                    acc[mh * 4 + mf][nh * 2 + nf] =
                        __builtin_amdgcn_mfma_f32_16x16x32_bf16(
                            aq[mf][ks], bq_[nf][ks], acc[mh * 4 + mf][nh * 2 + nf], 0, 0, 0);
    };

    stage(0, 0);
    stage(1, 1);
    // outstanding: 16. steady state: wait(8) -> tile i landed, tile i+1 in flight.
    #pragma unroll 1
    for (int i = 0; i < 16; ++i) {
        const int cur = i & 1;
        if (i < 15) { WAIT_VM8(); } else { WAIT_VM0(); }
        BAR();
        // quadrant order with fragment reuse; compiler schedules ds_reads freely
        ldA(cur, 0);
        ldB(cur, 0, bA);
        mma(0, 0, bA);
        ldB(cur, 1, bB);
        mma(0, 1, bB);
        ldA(cur, 1);
        mma(1, 1, bB);
        mma(1, 0, bA);
        BAR();                       // all waves done reading buf cur
        if (i < 14) stage(cur, i + 2);
    }

    // ---- epilogue ----
    const int h = nt * 4 + wc;                 // wave wc owns one head
    const int b = m0 >> 10;                    // 256-row tile never crosses batch
    const int lbase = (m0 & 1023) + wr * 128;

    float bb[4];
    #pragma unroll
    for (int cn = 0; cn < 4; ++cn)
        bb[cn] = bias[h * 64 + (cn >> 1) * 32 + (cn & 1) * 16 + c];

    if (z < 2) {
        u16* dst = (z == 0) ? qws : kws;
        const float scale = (z == 0) ? 0.125f : 1.0f;
        u16* dbase = dst + (size_t)(b * 16 + h) * 1024 * 64;
        #pragma unroll
        for (int mi = 0; mi < 8; ++mi) {
            const int ro = (mi >> 2) * 64 + (mi & 3) * 16;
            const int rowb = lbase + ro + quad * 4;
            #pragma unroll
            for (int rr = 0; rr < 4; ++rr) {
                u16* drow = dbase + (size_t)(rowb + rr) * 64;
                #pragma unroll
                for (int cn = 0; cn < 4; ++cn) {
                    const int hd = (cn >> 1) * 32 + (cn & 1) * 16 + c;
                    drow[hd] = f2bf((acc[mi][cn][rr] + bb[cn]) * scale);
                }
            }
        }
    } else {
        // V epilogue via LDS-bounce (lds is free after the K-loop's final BAR).
        u16* lw = &lds[0][0][0] + w * 8192;
        #pragma unroll
        for (int mi = 0; mi < 8; ++mi) {
            const int ll = (mi >> 2) * 64 + (mi & 3) * 16 + quad * 4;
            #pragma unroll
            for (int cn = 0; cn < 4; ++cn) {
                const int hd = (cn >> 1) * 32 + (cn & 1) * 16 + c;
                ushort4 pk;
                pk.x = f2bf(acc[mi][cn][0] + bb[cn]);
                pk.y = f2bf(acc[mi][cn][1] + bb[cn]);
                pk.z = f2bf(acc[mi][cn][2] + bb[cn]);
                pk.w = f2bf(acc[mi][cn][3] + bb[cn]);
                *(ushort4*)(lw + hd * 128 + (ll ^ ((hd & 15) << 3))) = pk;
            }
        }
        u16* dbase = vtws + (size_t)(b * 16 + h) * 64 * 1024;
        #pragma unroll
        for (int it = 0; it < 16; ++it) {
            const int s = it * 64 + lane;      // 0..1023 = 64 hd x 16 chunks
            const int hd = s >> 4, ck = s & 15;
            short8 v = *(const short8*)(lw + hd * 128 + ((ck * 8) ^ ((hd & 15) << 3)));
            *(short8*)(dbase + (size_t)hd * 1024 + lbase + ck * 8) = v;
        }
    }
}

// ---------------------------------------------------------------------------
// Output projection v4: 2-phase counted pipeline (unchanged this round)
// ---------------------------------------------------------------------------
__global__ __launch_bounds__(256) void gemm_out(
    const u16* __restrict__ A, const u16* __restrict__ Wot,
    const float* __restrict__ bo, float* __restrict__ out)
{
    __shared__ u16 As[2][128 * 64];   // 32 KB
    __shared__ u16 Bs[2][64 * 64];    // 16 KB
    const int f = blockIdx.x;
    const int xcd = f & 7, k = f >> 3;
    const int m0 = (xcd * 4 + (k & 3)) * 128;
    const int n0 = (k >> 2) * 64;
    const int t = threadIdx.x;
    const int w = t >> 6, lane = t & 63;
    const int quad = lane >> 4, c = lane & 15;
    const int cx = c & 7;

    const int sr = w * 8 + (lane >> 3);
    const int gch = (lane & 7) ^ ((lane >> 3) & 7);
    const u16* gA = A + (size_t)(m0 + sr) * 1024 + gch * 8;
    const u16* gB = Wot + (size_t)(n0 + sr) * 1024 + gch * 8;

    const int arow = (w >> 1) * 64 + c;
    const int brow = (w & 1) * 32 + c;

    auto stage = [&](int par, int kt) {        // 6 glds16 per thread
        #pragma unroll
        for (int i = 0; i < 4; ++i)
            glds16(As[par] + (i * 32 + w * 8) * 64, gA + (size_t)i * 32 * 1024 + kt);
        #pragma unroll
        for (int i = 0; i < 2; ++i)
            glds16(Bs[par] + (i * 32 + w * 8) * 64, gB + (size_t)i * 32 * 1024 + kt);
    };

    f32x4 acc[4][2] = {};
    stage(0, 0);
    stage(1, 64);
    // outstanding: 12. steady state: wait(6) -> tile i landed, tile i+1 in flight.
    #pragma unroll 1
    for (int i = 0; i < 16; ++i) {
        const int cur = i & 1;
        if (i < 15) { WAIT_VM6(); } else { WAIT_VM0(); }
        BAR();
        #pragma unroll
        for (int kh = 0; kh < 2; ++kh) {
            const int ch = (kh * 4 + quad);
            short8 af[4], bf[2];
            #pragma unroll
            for (int rs = 0; rs < 4; ++rs)
                af[rs] = *(const short8*)(As[cur] + (arow + rs * 16) * 64 + (ch ^ cx) * 8);
            #pragma unroll
            for (int cs = 0; cs < 2; ++cs)
                bf[cs] = *(const short8*)(Bs[cur] + (brow + cs * 16) * 64 + (ch ^ cx) * 8);
            #pragma unroll
            for (int rs = 0; rs < 4; ++rs)
                #pragma unroll
                for (int cs = 0; cs < 2; ++cs)
                    acc[rs][cs] = __builtin_amdgcn_mfma_f32_16x16x32_bf16(
                        af[rs], bf[cs], acc[rs][cs], 0, 0, 0);
        }
        BAR();                       // all waves done reading buf cur
        if (i < 14) stage(cur, (i + 2) * 64);
    }

    const int nb = n0 + (w & 1) * 32;
    float bb[2];
    #pragma unroll
    for (int cs = 0; cs < 2; ++cs) bb[cs] = bo[nb + cs * 16 + c];

    #pragma unroll
    for (int rs = 0; rs < 4; ++rs) {
        #pragma unroll
        for (int r = 0; r < 4; ++r) {
            const int row = m0 + (w >> 1) * 64 + rs * 16 + quad * 4 + r;
            float* orow = out + (size_t)row * 1024 + nb;
            #pragma unroll
            for (int cs = 0; cs < 2; ++cs)
                orow[cs * 16 + c] = acc[rs][cs][r] + bb[cs];
        }
    }
}

// ---------------------------------------------------------------------------
// MFMA flash attention v10 = v8 + swapped-QK in-register P packing (T12-16x16).
// mfma(K,Q) instead of mfma(Q,K): SAME fragments, swapped args -> lane (c,quad)
// reg r holds P[q=c][k=nt*16+quad*4+r] — 4 consecutive k. The exp'd P packs to
// ONE ds_write_b64 per nt (4 b64 writes/rb vs 16 scalar b16), read back as 4
// XOR-swizzled ds_read_b64. Softmax sum is lane-local per q: reduce = 2
// shfl_xor(16,32); 1/sum broadcast to O-row owners via 4 shfl. S is bitwise
// identical (same products, same inner-d order); only denom add-order changes.
// ---------------------------------------------------------------------------
__global__ __launch_bounds__(256) void attn_mfma(
    const u16* __restrict__ qws, const u16* __restrict__ kws,
    const u16* __restrict__ vtws, u16* __restrict__ multi,
    float* __restrict__ resid)
{
    __shared__ u16 Ks[2][64 * 64];     // [par][key][dim], chunk-swizzled (16 KB)
    __shared__ u16 Vs[2][64 * 64];     // [par][dim][key], chunk-swizzled (16 KB)
    __shared__ u16 Ps[4][16 * 64];     // per-wave P [16 q][16 b64-slots] (8 KB)
    const int t = threadIdx.x;
    const int wave = t >> 6, lane = t & 63;
    const int quad = lane >> 4, c = lane & 15;
    const int cx = c & 7;
    const int f = blockIdx.x;                  // 512 blocks
    const int xcd = f & 7, j = f >> 3;         // j 0..63
    const int bh = xcd * 8 + (j & 7);          // 8 heads per XCD (KV L2-resident)
    const int qt = j >> 3;                     // 0..7
    const int b = bh >> 4, h = bh & 15;
    const int q0 = qt * 128 + wave * 32;       // 32 q-rows per wave

    const u16* qb = qws + ((size_t)bh * 1024 + q0) * 64;
    const u16* kb = kws + (size_t)bh * 65536;
    const u16* vb = vtws + (size_t)bh * 65536;

    // Q fragments for 2 row-blocks (rows rb*16 + c), k-halves 0/1
    short8 qa[2][2];
    #pragma unroll
    for (int rb = 0; rb < 2; ++rb) {
        qa[rb][0] = *(const short8*)(qb + (size_t)(rb * 16 + c) * 64 + quad * 8);
        qa[rb][1] = *(const short8*)(qb + (size_t)(rb * 16 + c) * 64 + 32 + quad * 8);
    }

    const int srow = wave * 16 + (lane >> 3);
    const int gch = (lane & 7) ^ ((lane >> 3) & 7);
    const u16* gK0 = kb + (size_t)srow * 64 + gch * 8;
    const u16* gK1 = kb + (size_t)(srow + 8) * 64 + gch * 8;
    const u16* gV0 = vb + (size_t)srow * 1024 + gch * 8;
    const u16* gV1 = vb + (size_t)(srow + 8) * 1024 + gch * 8;

    // 4 glds16 per stage -> vmcnt +4; steady-state outstanding = 8 (2 tiles)
    auto stage = [&](int par, int kt) {
        glds16(Ks[par] + (wave * 16) * 64,     gK0 + (size_t)kt * 64);
        glds16(Ks[par] + (wave * 16 + 8) * 64, gK1 + (size_t)kt * 64);
        glds16(Vs[par] + (wave * 16) * 64,     gV0 + kt);
        glds16(Vs[par] + (wave * 16 + 8) * 64, gV1 + kt);
    };

    f32x4 O[2][4] = {};                // [rb][nt]
    float ps[2] = {0.f, 0.f};          // per-lane: q=c partial denom
    u16* pw = &Ps[wave][0];
    const int sw = (c & 7) << 1;       // per-row b64-slot swizzle (bijective XOR)

    stage(0, 0);
    stage(1, 64);

    #pragma unroll 1
    for (int i = 0; i < 16; ++i) {
        const int cur = i & 1;
        if (i < 15) { WAIT_VM4(); } else { WAIT_VM0(); }  // tile i landed
        BAR();

        const u16* Kc = Ks[cur];
        const u16* Vc = Vs[cur];

        // hoist K/V fragments once per tile; reused by both row-blocks
        short8 kf[4][2], vf[4][2];
        #pragma unroll
        for (int nt = 0; nt < 4; ++nt) {
            const u16* kr = Kc + (nt * 16 + c) * 64;
            kf[nt][0] = *(const short8*)(kr + ((quad ^ cx)) * 8);
            kf[nt][1] = *(const short8*)(kr + (((4 + quad) ^ cx)) * 8);
            const u16* vr = Vc + (nt * 16 + c) * 64;
            vf[nt][0] = *(const short8*)(vr + ((quad ^ cx)) * 8);
            vf[nt][1] = *(const short8*)(vr + (((4 + quad) ^ cx)) * 8);
        }

        #pragma unroll
        for (int rb = 0; rb < 2; ++rb) {
            // swapped QK^T: S[k][q]; lane reg r = P[q=c][k=nt*16+quad*4+r]
            f32x4 s[4];
            __builtin_amdgcn_s_setprio(1);
            #pragma unroll
            for (int nt = 0; nt < 4; ++nt) {
                f32x4 z = {};
                z = __builtin_amdgcn_mfma_f32_16x16x32_bf16(kf[nt][0], qa[rb][0], z, 0, 0, 0);
                z = __builtin_amdgcn_mfma_f32_16x16x32_bf16(kf[nt][1], qa[rb][1], z, 0, 0, 0);
                s[nt] = z;
            }
            __builtin_amdgcn_s_setprio(0);

            // P store: row q=c, b64 slot (nt*4+quad) XOR-swizzled; 4 packed k
            #pragma unroll
            for (int nt = 0; nt < 4; ++nt) {
                float p0 = __expf(s[nt][0]);
                float p1 = __expf(s[nt][1]);
                float p2 = __expf(s[nt][2]);
                float p3 = __expf(s[nt][3]);
                ps[rb] += (p0 + p1) + (p2 + p3);
                ushort4 pk;
                pk.x = (u16)(__float_as_uint(p0) >> 16);
                pk.y = (u16)(__float_as_uint(p1) >> 16);
                pk.z = (u16)(__float_as_uint(p2) >> 16);
                pk.w = (u16)(__float_as_uint(p3) >> 16);
                *(ushort4*)(pw + c * 64 + (((nt * 4 + quad) ^ sw) * 4)) = pk;
            }
            // P read (PV A-operand): row q=c, k = quad*8+jj (pa0), 32+quad*8+jj (pa1)
            ushort4 r0 = *(const ushort4*)(pw + c * 64 + (((2 * quad + 0) ^ sw) * 4));
            ushort4 r1 = *(const ushort4*)(pw + c * 64 + (((2 * quad + 1) ^ sw) * 4));
            ushort4 r2 = *(const ushort4*)(pw + c * 64 + (((8 + 2 * quad + 0) ^ sw) * 4));
            ushort4 r3 = *(const ushort4*)(pw + c * 64 + (((8 + 2 * quad + 1) ^ sw) * 4));
            short8 pa0, pa1;
            pa0[0] = (short)r0.x; pa0[1] = (short)r0.y; pa0[2] = (short)r0.z; pa0[3] = (short)r0.w;
            pa0[4] = (short)r1.x; pa0[5] = (short)r1.y; pa0[6] = (short)r1.z; pa0[7] = (short)r1.w;
            pa1[0] = (short)r2.x; pa1[1] = (short)r2.y; pa1[2] = (short)r2.z; pa1[3] = (short)r2.w;
            pa1[4] = (short)r3.x; pa1[5] = (short)r3.y; pa1[6] = (short)r3.z; pa1[7] = (short)r3.w;

            __builtin_amdgcn_s_setprio(1);
            #pragma unroll
            for (int nt = 0; nt < 4; ++nt) {
                O[rb][nt] = __builtin_amdgcn_mfma_f32_16x16x32_bf16(pa0, vf[nt][0], O[rb][nt], 0, 0, 0);
                O[rb][nt] = __builtin_amdgcn_mfma_f32_16x16x32_bf16(pa1, vf[nt][1], O[rb][nt], 0, 0, 0);
            }
            __builtin_amdgcn_s_setprio(0);
        }

        BAR();                         // all waves done reading buf cur
        if (i < 14) stage(cur, (i + 2) * 64);
    }

    #pragma unroll
    for (int rb = 0; rb < 2; ++rb) {
        // denom: lane holds partial for q=c over k≡{quad's slots}; sum quads
        float sum = ps[rb];
        sum += __shfl_xor(sum, 16);
        sum += __shfl_xor(sum, 32);
        float invq = 1.0f / sum;               // valid per lane's q=c
        float inv[4];
        #pragma unroll
        for (int r = 0; r < 4; ++r) inv[r] = __shfl(invq, quad * 4 + r);

        u16* ob = multi + ((size_t)b * 1024 + q0 + rb * 16 + quad * 4) * 1024 + h * 64 + c;
        #pragma unroll
        for (int r = 0; r < 4; ++r) {
            u16* orow = ob + (size_t)r * 1024;
            orow[0]  = f2bf(O[rb][0][r] * inv[r]);
            orow[16] = f2bf(O[rb][1][r] * inv[r]);
            orow[32] = f2bf(O[rb][2][r] * inv[r]);
            orow[48] = f2bf(O[rb][3][r] * inv[r]);
        }

        // resid epilogue: lane holds Q[q0+rb*16+c][quad*8..] in qa[rb] (scaled 1/8)
        float* rr = resid + ((size_t)b * 1024 + q0 + rb * 16 + c) * 1024 + h * 64;
        #pragma unroll
        for (int jj = 0; jj < 8; ++jj) {
            rr[quad * 8 + jj]      = bf2f((u16)qa[rb][0][jj]) * 8.0f;
            rr[32 + quad * 8 + jj] = bf2f((u16)qa[rb][1][jj]) * 8.0f;
        }
    }
}

extern "C" void kernel_launch(void* const* d_in, const int* in_sizes, int n_in,
                              void* d_out, int out_size, void* d_ws, size_t ws_size,
                              hipStream_t stream) {
    const float* queries = (const float*)d_in[0];
    const float* context = (const float*)d_in[1];
    const float* Wq = (const float*)d_in[2];
    const float* bq = (const float*)d_in[3];
    const float* Wk = (const float*)d_in[4];
    const float* bk = (const float*)d_in[5];
    const float* Wv = (const float*)d_in[6];
    const float* bv = (const float*)d_in[7];
    const float* Wo = (const float*)d_in[8];
    const float* bo = (const float*)d_in[9];

    float* out = (float*)d_out;                     // [4,1024,1024] f32
    float* resid = out + (size_t)4 * 1024 * 1024;   // [4,1024,1024] f32

    const size_t M1 = 1024 * 1024;
    u16* Aq   = (u16*)d_ws;          // 4M
    u16* Ac   = Aq + 4 * M1;         // 4M
    u16* Wqt  = Ac + 4 * M1;         // 1M
    u16* Wkt  = Wqt + M1;            // 1M
    u16* Wvt  = Wkt + M1;            // 1M
    u16* Wot  = Wvt + M1;            // 1M
    u16* qws  = Wot + M1;            // 4M (pre-scaled 0.125)
    u16* kws  = qws + 4 * M1;        // 4M
    u16* vtws = kws + 4 * M1;        // 4M [B,H,64,1024]
    u16* mws  = vtws + 4 * M1;       // 4M [B,1024,1024]

    prep<<<5120, 256, 0, stream>>>(queries, context, Wq, Wk, Wv, Wo,
                                   Aq, Ac, Wqt, Wkt, Wvt, Wot);
    gemm_qkv2<<<192, 512, 0, stream>>>(Aq, Ac, Wqt, Wkt, Wvt,
                                       bq, bk, bv, qws, kws, vtws);
    attn_mfma<<<512, 256, 0, stream>>>(qws, kws, vtws, mws, resid);
    gemm_out<<<512, 256, 0, stream>>>(mws, Wot, bo, out);
}